// Round 1
// baseline (499.205 us; speedup 1.0000x reference)
//
#include <hip/hip_runtime.h>
#include <hip/hip_bf16.h>

#define Bc   4
#define Pc   12
#define Nc   4096
#define Hc   64
#define TDc  128
#define Ec   65536
#define BPc  48
#define NHc  (Nc*Hc)      // 262144
#define ROWS (BPc*Nc)     // 196608
#define EPSc 1e-5f

// ---------------- time projection: t[b,h] = MLP(time[b,:]) ----------------
__global__ void k_tproj(const float* __restrict__ timev,
                        const float* __restrict__ w1, const float* __restrict__ b1,
                        const float* __restrict__ w2, const float* __restrict__ b2,
                        float* __restrict__ t_out) {
    __shared__ float s_time[Bc * TDc];
    __shared__ float s_hid[Bc * Hc];
    int t = threadIdx.x;
    for (int i = t; i < Bc * TDc; i += 256) s_time[i] = timev[i];
    __syncthreads();
    int b = t >> 6, j = t & 63;
    float acc = b1[j];
    for (int k = 0; k < TDc; ++k) acc = fmaf(s_time[b * TDc + k], w1[j * TDc + k], acc);
    s_hid[b * Hc + j] = fmaxf(acc, 0.f);
    __syncthreads();
    float acc2 = b2[j];
    for (int k = 0; k < Hc; ++k) acc2 = fmaf(s_hid[b * Hc + k], w2[j * Hc + k], acc2);
    t_out[b * Hc + j] = acc2;
}

// ---------------- degree count ----------------
__global__ void k_deg(const int* __restrict__ col, int* __restrict__ deg) {
    int e = blockIdx.x * 256 + threadIdx.x;
    atomicAdd(&deg[col[e]], 1);
}

// ---------------- exclusive scan over 4096 degrees + dis = deg^-1/2 ----------------
__global__ __launch_bounds__(1024) void k_scan(const int* __restrict__ deg,
                                               int* __restrict__ offs,
                                               int* __restrict__ cursor,
                                               float* __restrict__ dis) {
    __shared__ int part[1024];
    int t = threadIdx.x;
    int d0 = deg[t * 4], d1 = deg[t * 4 + 1], d2 = deg[t * 4 + 2], d3 = deg[t * 4 + 3];
    part[t] = d0 + d1 + d2 + d3;
    __syncthreads();
    for (int off = 1; off < 1024; off <<= 1) {
        int v = (t >= off) ? part[t - off] : 0;
        __syncthreads();
        part[t] += v;
        __syncthreads();
    }
    int base = (t ? part[t - 1] : 0);
    offs[t * 4]     = base;
    offs[t * 4 + 1] = base + d0;
    offs[t * 4 + 2] = base + d0 + d1;
    offs[t * 4 + 3] = base + d0 + d1 + d2;
    if (t == 1023) offs[4096] = part[1023];
    cursor[t * 4]     = base;
    cursor[t * 4 + 1] = base + d0;
    cursor[t * 4 + 2] = base + d0 + d1;
    cursor[t * 4 + 3] = base + d0 + d1 + d2;
    dis[t * 4]     = d0 > 0 ? rsqrtf((float)d0) : 0.f;
    dis[t * 4 + 1] = d1 > 0 ? rsqrtf((float)d1) : 0.f;
    dis[t * 4 + 2] = d2 > 0 ? rsqrtf((float)d2) : 0.f;
    dis[t * 4 + 3] = d3 > 0 ? rsqrtf((float)d3) : 0.f;
}

// ---------------- CSR fill ----------------
__global__ void k_fill(const int* __restrict__ ei, int* __restrict__ cursor,
                       const float* __restrict__ dis,
                       int* __restrict__ csr_src, float* __restrict__ csr_w) {
    int e = blockIdx.x * 256 + threadIdx.x;
    int r = ei[e], c = ei[Ec + e];
    int pos = atomicAdd(&cursor[c], 1);
    csr_src[pos] = r;
    csr_w[pos] = dis[r] * dis[c];
}

// ---------------- cond MLP + add x -> h1; LN1 partial stats ----------------
__global__ __launch_bounds__(256) void k_condmlp(const float* __restrict__ cond,
                                                 const float* __restrict__ x,
                                                 const float* __restrict__ w1, const float* __restrict__ b1,
                                                 const float* __restrict__ w2, const float* __restrict__ b2,
                                                 float* __restrict__ h1, float* __restrict__ part1) {
    int row = blockIdx.x * 256 + threadIdx.x;
    const float* cr = cond + (size_t)row * Hc;
    float r[Hc];
    #pragma unroll
    for (int k = 0; k < Hc; k += 4) {
        float4 v = *(const float4*)(cr + k);
        r[k] = v.x; r[k + 1] = v.y; r[k + 2] = v.z; r[k + 3] = v.w;
    }
    float hid[Hc];
    #pragma unroll
    for (int j = 0; j < Hc; ++j) {
        float a = b1[j];
        #pragma unroll
        for (int k = 0; k < Hc; ++k) a = fmaf(r[k], w1[j * Hc + k], a);
        hid[j] = fmaxf(a, 0.f);
    }
    const float* xr = x + (size_t)row * Hc;
    float* hr = h1 + (size_t)row * Hc;
    float s = 0.f, ss = 0.f;
    #pragma unroll
    for (int j = 0; j < Hc; j += 4) {
        float4 xv = *(const float4*)(xr + j);
        float o[4];
        #pragma unroll
        for (int q = 0; q < 4; ++q) {
            float a = b2[j + q];
            #pragma unroll
            for (int k = 0; k < Hc; ++k) a = fmaf(hid[k], w2[(j + q) * Hc + k], a);
            o[q] = a;
        }
        o[0] += xv.x; o[1] += xv.y; o[2] += xv.z; o[3] += xv.w;
        float4 ov = {o[0], o[1], o[2], o[3]};
        *(float4*)(hr + j) = ov;
        #pragma unroll
        for (int q = 0; q < 4; ++q) { s += o[q]; ss += o[q] * o[q]; }
    }
    // wave reduce (deterministic tree)
    for (int off = 32; off; off >>= 1) { s += __shfl_down(s, off); ss += __shfl_down(ss, off); }
    if ((threadIdx.x & 63) == 0) {
        int bp = row >> 12;               // row / N
        int i  = (row >> 6) & 63;         // wave index within bp
        part1[(bp * 64 + i) * 2]     = s;
        part1[(bp * 64 + i) * 2 + 1] = ss;
    }
}

// ---------------- finalize LN stats: mu, rsqrt(var+eps) per bp ----------------
__global__ __launch_bounds__(256) void k_finalize(const float* __restrict__ part, int cnt,
                                                  float* __restrict__ murs) {
    int bp = blockIdx.x;
    float s = 0.f, ss = 0.f;
    for (int i = threadIdx.x; i < cnt; i += 256) {
        s  += part[(bp * cnt + i) * 2];
        ss += part[(bp * cnt + i) * 2 + 1];
    }
    __shared__ float ls[4], lss[4];
    for (int off = 32; off; off >>= 1) { s += __shfl_down(s, off); ss += __shfl_down(ss, off); }
    int w = threadIdx.x >> 6, l = threadIdx.x & 63;
    if (l == 0) { ls[w] = s; lss[w] = ss; }
    __syncthreads();
    if (threadIdx.x == 0) {
        s  = ls[0] + ls[1] + ls[2] + ls[3];
        ss = lss[0] + lss[1] + lss[2] + lss[3];
        float mu = s / (float)NHc;
        float var = ss / (float)NHc - mu * mu;
        murs[bp * 2]     = mu;
        murs[bp * 2 + 1] = rsqrtf(var + EPSc);
    }
}

// ---------------- apply LN1: h1n = (h1-mu)*rs*gn_w + gn_b ----------------
__global__ __launch_bounds__(256) void k_norm1(const float* __restrict__ h1,
                                               const float* __restrict__ murs,
                                               const float* __restrict__ gnw, const float* __restrict__ gnb,
                                               float* __restrict__ h1n) {
    size_t i = (size_t)blockIdx.x * 256 + threadIdx.x;  // float4 index
    size_t e0 = i * 4;
    int bp = (int)(e0 >> 18);           // / NHc
    int g  = (int)(e0 & (NHc - 1));
    float mu = murs[bp * 2], rs = murs[bp * 2 + 1];
    float4 v = ((const float4*)h1)[i];
    float4 wv = *(const float4*)(gnw + g);
    float4 bv = *(const float4*)(gnb + g);
    v.x = (v.x - mu) * rs * wv.x + bv.x;
    v.y = (v.y - mu) * rs * wv.y + bv.y;
    v.z = (v.z - mu) * rs * wv.z + bv.z;
    v.w = (v.w - mu) * rs * wv.w + bv.w;
    ((float4*)h1n)[i] = v;
}

// ---------------- LGConv gather + add t -> h2; LN2 partial stats ----------------
__global__ __launch_bounds__(256) void k_gather(const int* __restrict__ offs,
                                                const int* __restrict__ csr_src,
                                                const float* __restrict__ csr_w,
                                                const float* __restrict__ h1n,
                                                const float* __restrict__ t_in,
                                                float* __restrict__ h2,
                                                float* __restrict__ part2) {
    int n = blockIdx.x;
    int wave = threadIdx.x >> 6;
    int lane = threadIdx.x & 63;
    int bp = blockIdx.y * 4 + wave;
    int b = bp / Pc;
    const float* base = h1n + (size_t)bp * NHc;
    int s0 = offs[n], s1 = offs[n + 1];
    float acc = 0.f;
    for (int idx = s0; idx < s1; ++idx) {
        int src = csr_src[idx];
        float w = csr_w[idx];
        acc = fmaf(w, base[src * Hc + lane], acc);
    }
    acc += t_in[b * Hc + lane];
    h2[(size_t)bp * NHc + n * Hc + lane] = acc;
    float s = acc, ss = acc * acc;
    for (int off = 32; off; off >>= 1) { s += __shfl_down(s, off); ss += __shfl_down(ss, off); }
    if (lane == 0) {
        part2[((size_t)bp * Nc + n) * 2]     = s;
        part2[((size_t)bp * Nc + n) * 2 + 1] = ss;
    }
}

// ---------------- apply LN2 + 1x1 conv over P ----------------
__global__ __launch_bounds__(256) void k_conv(const float* __restrict__ h2,
                                              const float* __restrict__ murs,
                                              const float* __restrict__ tnw, const float* __restrict__ tnb,
                                              const float* __restrict__ cw, const float* __restrict__ cb,
                                              float* __restrict__ out) {
    int tid = blockIdx.x * 256 + threadIdx.x;  // B * NHc/4 threads
    int b  = tid >> 16;           // / (NHc/4)
    int i4 = tid & 65535;
    size_t e0 = (size_t)i4 * 4;
    float4 w4 = *(const float4*)(tnw + e0);
    float4 b4 = *(const float4*)(tnb + e0);
    float v[Pc][4];
    #pragma unroll
    for (int p = 0; p < Pc; ++p) {
        int bp = b * Pc + p;
        float mu = murs[bp * 2], rs = murs[bp * 2 + 1];
        float4 h = *(const float4*)(h2 + (size_t)bp * NHc + e0);
        v[p][0] = (h.x - mu) * rs * w4.x + b4.x;
        v[p][1] = (h.y - mu) * rs * w4.y + b4.y;
        v[p][2] = (h.z - mu) * rs * w4.z + b4.z;
        v[p][3] = (h.w - mu) * rs * w4.w + b4.w;
    }
    #pragma unroll
    for (int q = 0; q < Pc; ++q) {
        float cbq = cb[q];
        float o0 = cbq, o1 = cbq, o2 = cbq, o3 = cbq;
        #pragma unroll
        for (int p = 0; p < Pc; ++p) {
            float wqp = cw[q * Pc + p];
            o0 = fmaf(v[p][0], wqp, o0);
            o1 = fmaf(v[p][1], wqp, o1);
            o2 = fmaf(v[p][2], wqp, o2);
            o3 = fmaf(v[p][3], wqp, o3);
        }
        float4 o = {o0, o1, o2, o3};
        *(float4*)(out + (size_t)(b * Pc + q) * NHc + e0) = o;
    }
}

extern "C" void kernel_launch(void* const* d_in, const int* in_sizes, int n_in,
                              void* d_out, int out_size, void* d_ws, size_t ws_size,
                              hipStream_t stream) {
    (void)in_sizes; (void)n_in; (void)out_size; (void)ws_size;
    const float* x     = (const float*)d_in[0];
    const int*   ei    = (const int*)  d_in[1];
    const float* timev = (const float*)d_in[2];
    const float* cond  = (const float*)d_in[3];
    const float* tp_w1 = (const float*)d_in[4];
    const float* tp_b1 = (const float*)d_in[5];
    const float* tp_w2 = (const float*)d_in[6];
    const float* tp_b2 = (const float*)d_in[7];
    const float* cp_w1 = (const float*)d_in[8];
    const float* cp_b1 = (const float*)d_in[9];
    const float* cp_w2 = (const float*)d_in[10];
    const float* cp_b2 = (const float*)d_in[11];
    const float* gn_w  = (const float*)d_in[12];
    const float* gn_b  = (const float*)d_in[13];
    const float* tn_w  = (const float*)d_in[14];
    const float* tn_b  = (const float*)d_in[15];
    const float* cw    = (const float*)d_in[16];
    const float* cb    = (const float*)d_in[17];
    float* out = (float*)d_out;

    char* w = (char*)d_ws;
    size_t off = 0;
    auto alloc = [&](size_t bytes) {
        void* p = w + off;
        off = (off + bytes + 255) & ~(size_t)255;
        return p;
    };
    float* buf1    = (float*)alloc((size_t)ROWS * Hc * sizeof(float)); // h1, then h2
    float* part1   = (float*)alloc((size_t)BPc * 64 * 2 * 4);
    float* part2   = (float*)alloc((size_t)BPc * Nc * 2 * 4);
    float* murs1   = (float*)alloc(96 * 4);
    float* murs2   = (float*)alloc(96 * 4);
    float* t_ws    = (float*)alloc(256 * 4);
    float* dis     = (float*)alloc(Nc * 4);
    float* csr_w   = (float*)alloc(Ec * 4);
    int*   deg     = (int*)alloc(Nc * 4);
    int*   offs    = (int*)alloc((Nc + 1) * 4);
    int*   cursor  = (int*)alloc(Nc * 4);
    int*   csr_src = (int*)alloc(Ec * 4);
    float* h1n = out;  // reuse output buffer as scratch for normalized h1

    hipMemsetAsync(deg, 0, Nc * sizeof(int), stream);
    k_tproj<<<1, 256, 0, stream>>>(timev, tp_w1, tp_b1, tp_w2, tp_b2, t_ws);
    k_deg<<<Ec / 256, 256, 0, stream>>>(ei + Ec, deg);
    k_scan<<<1, 1024, 0, stream>>>(deg, offs, cursor, dis);
    k_fill<<<Ec / 256, 256, 0, stream>>>(ei, cursor, dis, csr_src, csr_w);
    k_condmlp<<<ROWS / 256, 256, 0, stream>>>(cond, x, cp_w1, cp_b1, cp_w2, cp_b2, buf1, part1);
    k_finalize<<<BPc, 256, 0, stream>>>(part1, 64, murs1);
    k_norm1<<<(ROWS * Hc / 4) / 256, 256, 0, stream>>>(buf1, murs1, gn_w, gn_b, h1n);
    k_gather<<<dim3(Nc, BPc / 4), 256, 0, stream>>>(offs, csr_src, csr_w, h1n, t_ws, buf1, part2);
    k_finalize<<<BPc, 256, 0, stream>>>(part2, Nc, murs2);
    k_conv<<<(Bc * NHc / 4) / 256, 256, 0, stream>>>(buf1, murs2, tn_w, tn_b, cw, cb, out);
}

// Round 2
// 273.800 us; speedup vs baseline: 1.8232x; 1.8232x over previous
//
#include <hip/hip_runtime.h>
#include <hip/hip_bf16.h>

#define Bc   4
#define Pc   12
#define Nc   4096
#define Hc   64
#define TDc  128
#define Ec   65536
#define BPc  48
#define NHc  (Nc*Hc)      // 262144
#define ROWS (BPc*Nc)     // 196608
#define EPSc 1e-5f

typedef float f32x4 __attribute__((ext_vector_type(4)));
typedef short s16x4 __attribute__((ext_vector_type(4)));

__device__ inline short f2bf(float f) {
    union { float f; unsigned u; } v; v.f = f;
    unsigned r = v.u + 0x7FFFu + ((v.u >> 16) & 1u);
    return (short)(r >> 16);
}
__device__ inline s16x4 f2bf4(f32x4 v) {
    s16x4 o;
    o.x = f2bf(v.x); o.y = f2bf(v.y); o.z = f2bf(v.z); o.w = f2bf(v.w);
    return o;
}

// ---------------- time projection: t[b,h] = MLP(time[b,:]) ----------------
__global__ void k_tproj(const float* __restrict__ timev,
                        const float* __restrict__ w1, const float* __restrict__ b1,
                        const float* __restrict__ w2, const float* __restrict__ b2,
                        float* __restrict__ t_out) {
    __shared__ float s_time[Bc * TDc];
    __shared__ float s_hid[Bc * Hc];
    int t = threadIdx.x;
    for (int i = t; i < Bc * TDc; i += 256) s_time[i] = timev[i];
    __syncthreads();
    int b = t >> 6, j = t & 63;
    float acc = b1[j];
    for (int k = 0; k < TDc; ++k) acc = fmaf(s_time[b * TDc + k], w1[j * TDc + k], acc);
    s_hid[b * Hc + j] = fmaxf(acc, 0.f);
    __syncthreads();
    float acc2 = b2[j];
    for (int k = 0; k < Hc; ++k) acc2 = fmaf(s_hid[b * Hc + k], w2[j * Hc + k], acc2);
    t_out[b * Hc + j] = acc2;
}

// ---------------- degree count ----------------
__global__ void k_deg(const int* __restrict__ col, int* __restrict__ deg) {
    int e = blockIdx.x * 256 + threadIdx.x;
    atomicAdd(&deg[col[e]], 1);
}

// ---------------- exclusive scan over 4096 degrees + dis = deg^-1/2 ----------------
__global__ __launch_bounds__(1024) void k_scan(const int* __restrict__ deg,
                                               int* __restrict__ offs,
                                               int* __restrict__ cursor,
                                               float* __restrict__ dis) {
    __shared__ int part[1024];
    int t = threadIdx.x;
    int d0 = deg[t * 4], d1 = deg[t * 4 + 1], d2 = deg[t * 4 + 2], d3 = deg[t * 4 + 3];
    part[t] = d0 + d1 + d2 + d3;
    __syncthreads();
    for (int off = 1; off < 1024; off <<= 1) {
        int v = (t >= off) ? part[t - off] : 0;
        __syncthreads();
        part[t] += v;
        __syncthreads();
    }
    int base = (t ? part[t - 1] : 0);
    offs[t * 4]     = base;
    offs[t * 4 + 1] = base + d0;
    offs[t * 4 + 2] = base + d0 + d1;
    offs[t * 4 + 3] = base + d0 + d1 + d2;
    if (t == 1023) offs[4096] = part[1023];
    cursor[t * 4]     = base;
    cursor[t * 4 + 1] = base + d0;
    cursor[t * 4 + 2] = base + d0 + d1;
    cursor[t * 4 + 3] = base + d0 + d1 + d2;
    dis[t * 4]     = d0 > 0 ? rsqrtf((float)d0) : 0.f;
    dis[t * 4 + 1] = d1 > 0 ? rsqrtf((float)d1) : 0.f;
    dis[t * 4 + 2] = d2 > 0 ? rsqrtf((float)d2) : 0.f;
    dis[t * 4 + 3] = d3 > 0 ? rsqrtf((float)d3) : 0.f;
}

// ---------------- CSR fill ----------------
__global__ void k_fill(const int* __restrict__ ei, int* __restrict__ cursor,
                       const float* __restrict__ dis,
                       int* __restrict__ csr_src, float* __restrict__ csr_w) {
    int e = blockIdx.x * 256 + threadIdx.x;
    int r = ei[e], c = ei[Ec + e];
    int pos = atomicAdd(&cursor[c], 1);
    csr_src[pos] = r;
    csr_w[pos] = dis[r] * dis[c];
}

// ---------------- g1 = gather(gnw), g2 = gather(gnb) ----------------
__global__ __launch_bounds__(128) void k_gw(const int* __restrict__ offs,
                                            const int* __restrict__ csr_src,
                                            const float* __restrict__ csr_w,
                                            const float* __restrict__ gnw,
                                            const float* __restrict__ gnb,
                                            float* __restrict__ g1, float* __restrict__ g2) {
    int n = blockIdx.x;
    int wave = threadIdx.x >> 6, lane = threadIdx.x & 63;
    const float* src = wave ? gnb : gnw;
    float* dst = wave ? g2 : g1;
    int s0 = offs[n], s1 = offs[n + 1];
    float acc = 0.f;
    for (int i = s0; i < s1; ++i) acc = fmaf(csr_w[i], src[csr_src[i] * Hc + lane], acc);
    dst[n * Hc + lane] = acc;
}

// ---------------- MFMA cond-MLP: A = (x + mlp(cond)) * gnw; LN1 stats ----------------
// Layer L: D = W_tile[16x16] . (dataT)[16x16], legacy v_mfma_f32_16x16x16bf16_1k.
// A-frag: lane holds W[16t + (lane&15)][16kk + 4g + i]; B-frag: lane holds data[rowbase+(lane&15)][16kk+4g+i]
// D: col(lane&15)=data row r, row(4g+reg)=feature j -> j = 16t+4g+reg.
__global__ __launch_bounds__(256) void k_mlp(const float* __restrict__ cond,
                                             const float* __restrict__ x,
                                             const float* __restrict__ w1, const float* __restrict__ b1,
                                             const float* __restrict__ w2, const float* __restrict__ b2,
                                             const float* __restrict__ gnw,
                                             float* __restrict__ Aout, float* __restrict__ part1) {
    __shared__ __align__(16) short s_h[4][16][72];   // per-wave 16 rows x 64 feats (pad 72)
    int lane = threadIdx.x & 63;
    int wv   = threadIdx.x >> 6;
    int r = lane & 15, g = lane >> 4;

    s16x4 a1[4][4], a2[4][4];
    f32x4 b1q[4], b2q[4];
    #pragma unroll
    for (int t = 0; t < 4; ++t) {
        #pragma unroll
        for (int kk = 0; kk < 4; ++kk) {
            a1[t][kk] = f2bf4(*(const f32x4*)(w1 + (16 * t + r) * Hc + kk * 16 + 4 * g));
            a2[t][kk] = f2bf4(*(const f32x4*)(w2 + (16 * t + r) * Hc + kk * 16 + 4 * g));
        }
        b1q[t] = *(const f32x4*)(b1 + 16 * t + 4 * g);
        b2q[t] = *(const f32x4*)(b2 + 16 * t + 4 * g);
    }

    float s = 0.f, ss = 0.f;
    int blockRow = blockIdx.x * 256;
    #pragma unroll
    for (int c = 0; c < 4; ++c) {
        int row = blockRow + wv * 64 + c * 16 + r;
        // layer 1
        s16x4 bc[4];
        #pragma unroll
        for (int kk = 0; kk < 4; ++kk)
            bc[kk] = f2bf4(*(const f32x4*)(cond + (size_t)row * Hc + kk * 16 + 4 * g));
        #pragma unroll
        for (int t = 0; t < 4; ++t) {
            f32x4 acc = {0.f, 0.f, 0.f, 0.f};
            #pragma unroll
            for (int kk = 0; kk < 4; ++kk)
                acc = __builtin_amdgcn_mfma_f32_16x16x16bf16_1k(a1[t][kk], bc[kk], acc, 0, 0, 0);
            acc += b1q[t];
            f32x4 h;
            h.x = fmaxf(acc.x, 0.f); h.y = fmaxf(acc.y, 0.f);
            h.z = fmaxf(acc.z, 0.f); h.w = fmaxf(acc.w, 0.f);
            *(s16x4*)&s_h[wv][r][16 * t + 4 * g] = f2bf4(h);   // hid[r][j..j+3]
        }
        __syncthreads();
        // layer 2
        s16x4 hB[4];
        #pragma unroll
        for (int kk = 0; kk < 4; ++kk)
            hB[kk] = *(const s16x4*)&s_h[wv][r][16 * kk + 4 * g];
        #pragma unroll
        for (int t = 0; t < 4; ++t) {
            f32x4 acc = {0.f, 0.f, 0.f, 0.f};
            #pragma unroll
            for (int kk = 0; kk < 4; ++kk)
                acc = __builtin_amdgcn_mfma_f32_16x16x16bf16_1k(a2[t][kk], hB[kk], acc, 0, 0, 0);
            f32x4 x4 = *(const f32x4*)(x + (size_t)row * Hc + 16 * t + 4 * g);
            f32x4 o = acc + b2q[t] + x4;
            s  += o.x + o.y + o.z + o.w;
            ss += o.x * o.x + o.y * o.y + o.z * o.z + o.w * o.w;
            int n = row & (Nc - 1);
            f32x4 gw4 = *(const f32x4*)(gnw + n * Hc + 16 * t + 4 * g);
            *(f32x4*)(Aout + (size_t)row * Hc + 16 * t + 4 * g) = o * gw4;
        }
        __syncthreads();
    }
    for (int off = 32; off; off >>= 1) { s += __shfl_down(s, off); ss += __shfl_down(ss, off); }
    if (lane == 0) {
        int bp  = blockIdx.x >> 4;             // 16 blocks per bp
        int idx = (blockIdx.x & 15) * 4 + wv;  // 0..63
        part1[(bp * 64 + idx) * 2]     = s;
        part1[(bp * 64 + idx) * 2 + 1] = ss;
    }
}

// ---------------- finalize LN stats: mu, rsqrt(var+eps) per bp ----------------
__global__ __launch_bounds__(256) void k_finalize(const float* __restrict__ part, int cnt,
                                                  float* __restrict__ murs) {
    int bp = blockIdx.x;
    float s = 0.f, ss = 0.f;
    for (int i = threadIdx.x; i < cnt; i += 256) {
        s  += part[(bp * cnt + i) * 2];
        ss += part[(bp * cnt + i) * 2 + 1];
    }
    __shared__ float ls[4], lss[4];
    for (int off = 32; off; off >>= 1) { s += __shfl_down(s, off); ss += __shfl_down(ss, off); }
    int w = threadIdx.x >> 6, l = threadIdx.x & 63;
    if (l == 0) { ls[w] = s; lss[w] = ss; }
    __syncthreads();
    if (threadIdx.x == 0) {
        s  = ls[0] + ls[1] + ls[2] + ls[3];
        ss = lss[0] + lss[1] + lss[2] + lss[3];
        float mu = s / (float)NHc;
        float var = ss / (float)NHc - mu * mu;
        murs[bp * 2]     = mu;
        murs[bp * 2 + 1] = rsqrtf(var + EPSc);
    }
}

// ---------------- LGConv gather (normalized on the fly) + add t; LN2 stats ----------------
__global__ __launch_bounds__(256) void k_gather(const int* __restrict__ offs,
                                                const int* __restrict__ csr_src,
                                                const float* __restrict__ csr_w,
                                                const float* __restrict__ Ain,
                                                const float* __restrict__ g1,
                                                const float* __restrict__ g2,
                                                const float* __restrict__ murs,
                                                const float* __restrict__ t_in,
                                                float* __restrict__ h2,
                                                float* __restrict__ part2) {
    int n = blockIdx.x;
    int wave = threadIdx.x >> 6;
    int lane = threadIdx.x & 63;
    int bp = blockIdx.y * 4 + wave;
    int b = bp / Pc;
    const float* base = Ain + (size_t)bp * NHc;
    int s0 = offs[n], s1 = offs[n + 1];
    float acc = 0.f;
    for (int idx = s0; idx < s1; ++idx) {
        int src = csr_src[idx];
        float w = csr_w[idx];
        acc = fmaf(w, base[src * Hc + lane], acc);
    }
    float mu = murs[bp * 2], rs = murs[bp * 2 + 1];
    float val = rs * (acc - mu * g1[n * Hc + lane]) + g2[n * Hc + lane] + t_in[b * Hc + lane];
    h2[(size_t)bp * NHc + n * Hc + lane] = val;
    float s = val, ss = val * val;
    for (int off = 32; off; off >>= 1) { s += __shfl_down(s, off); ss += __shfl_down(ss, off); }
    if (lane == 0) {
        part2[((size_t)bp * Nc + n) * 2]     = s;
        part2[((size_t)bp * Nc + n) * 2 + 1] = ss;
    }
}

// ---------------- apply LN2 + 1x1 conv over P (h2 may alias out!) ----------------
__global__ __launch_bounds__(256) void k_conv(const float* h2,
                                              const float* __restrict__ murs,
                                              const float* __restrict__ tnw, const float* __restrict__ tnb,
                                              const float* __restrict__ cw, const float* __restrict__ cb,
                                              float* out) {
    int tid = blockIdx.x * 256 + threadIdx.x;  // B * NHc/4 threads
    int b  = tid >> 16;           // / (NHc/4)
    int i4 = tid & 65535;
    size_t e0 = (size_t)i4 * 4;
    float4 w4 = *(const float4*)(tnw + e0);
    float4 b4 = *(const float4*)(tnb + e0);
    float v[Pc][4];
    #pragma unroll
    for (int p = 0; p < Pc; ++p) {
        int bp = b * Pc + p;
        float mu = murs[bp * 2], rs = murs[bp * 2 + 1];
        float4 h = *(const float4*)(h2 + (size_t)bp * NHc + e0);
        v[p][0] = (h.x - mu) * rs * w4.x + b4.x;
        v[p][1] = (h.y - mu) * rs * w4.y + b4.y;
        v[p][2] = (h.z - mu) * rs * w4.z + b4.z;
        v[p][3] = (h.w - mu) * rs * w4.w + b4.w;
    }
    #pragma unroll
    for (int q = 0; q < Pc; ++q) {
        float cbq = cb[q];
        float o0 = cbq, o1 = cbq, o2 = cbq, o3 = cbq;
        #pragma unroll
        for (int p = 0; p < Pc; ++p) {
            float wqp = cw[q * Pc + p];
            o0 = fmaf(v[p][0], wqp, o0);
            o1 = fmaf(v[p][1], wqp, o1);
            o2 = fmaf(v[p][2], wqp, o2);
            o3 = fmaf(v[p][3], wqp, o3);
        }
        float4 o = {o0, o1, o2, o3};
        *(float4*)(out + (size_t)(b * Pc + q) * NHc + e0) = o;
    }
}

extern "C" void kernel_launch(void* const* d_in, const int* in_sizes, int n_in,
                              void* d_out, int out_size, void* d_ws, size_t ws_size,
                              hipStream_t stream) {
    (void)in_sizes; (void)n_in; (void)out_size; (void)ws_size;
    const float* x     = (const float*)d_in[0];
    const int*   ei    = (const int*)  d_in[1];
    const float* timev = (const float*)d_in[2];
    const float* cond  = (const float*)d_in[3];
    const float* tp_w1 = (const float*)d_in[4];
    const float* tp_b1 = (const float*)d_in[5];
    const float* tp_w2 = (const float*)d_in[6];
    const float* tp_b2 = (const float*)d_in[7];
    const float* cp_w1 = (const float*)d_in[8];
    const float* cp_b1 = (const float*)d_in[9];
    const float* cp_w2 = (const float*)d_in[10];
    const float* cp_b2 = (const float*)d_in[11];
    const float* gn_w  = (const float*)d_in[12];
    const float* gn_b  = (const float*)d_in[13];
    const float* tn_w  = (const float*)d_in[14];
    const float* tn_b  = (const float*)d_in[15];
    const float* cw    = (const float*)d_in[16];
    const float* cb    = (const float*)d_in[17];
    float* out = (float*)d_out;

    char* w = (char*)d_ws;
    size_t off = 0;
    auto alloc = [&](size_t bytes) {
        void* p = w + off;
        off = (off + bytes + 255) & ~(size_t)255;
        return p;
    };
    float* bufA    = (float*)alloc((size_t)ROWS * Hc * sizeof(float)); // A = h1*gnw
    float* part1   = (float*)alloc((size_t)BPc * 64 * 2 * 4);
    float* part2   = (float*)alloc((size_t)BPc * Nc * 2 * 4);
    float* murs1   = (float*)alloc(96 * 4);
    float* murs2   = (float*)alloc(96 * 4);
    float* t_ws    = (float*)alloc(256 * 4);
    float* dis     = (float*)alloc(Nc * 4);
    float* csr_w   = (float*)alloc(Ec * 4);
    float* g1      = (float*)alloc((size_t)NHc * 4);
    float* g2      = (float*)alloc((size_t)NHc * 4);
    int*   deg     = (int*)alloc(Nc * 4);
    int*   offs    = (int*)alloc((Nc + 1) * 4);
    int*   cursor  = (int*)alloc(Nc * 4);
    int*   csr_src = (int*)alloc(Ec * 4);
    float* h2 = out;  // gather output lives in d_out; k_conv is alias-safe

    hipMemsetAsync(deg, 0, Nc * sizeof(int), stream);
    k_tproj<<<1, 256, 0, stream>>>(timev, tp_w1, tp_b1, tp_w2, tp_b2, t_ws);
    k_deg<<<Ec / 256, 256, 0, stream>>>(ei + Ec, deg);
    k_scan<<<1, 1024, 0, stream>>>(deg, offs, cursor, dis);
    k_fill<<<Ec / 256, 256, 0, stream>>>(ei, cursor, dis, csr_src, csr_w);
    k_gw<<<Nc, 128, 0, stream>>>(offs, csr_src, csr_w, gn_w, gn_b, g1, g2);
    k_mlp<<<ROWS / 256, 256, 0, stream>>>(cond, x, cp_w1, cp_b1, cp_w2, cp_b2, gn_w, bufA, part1);
    k_finalize<<<BPc, 256, 0, stream>>>(part1, 64, murs1);
    k_gather<<<dim3(Nc, BPc / 4), 256, 0, stream>>>(offs, csr_src, csr_w, bufA, g1, g2,
                                                    murs1, t_ws, h2, part2);
    k_finalize<<<BPc, 256, 0, stream>>>(part2, Nc, murs2);
    k_conv<<<(Bc * NHc / 4) / 256, 256, 0, stream>>>(h2, murs2, tn_w, tn_b, cw, cb, out);
}

// Round 3
// 205.098 us; speedup vs baseline: 2.4340x; 1.3350x over previous
//
#include <hip/hip_runtime.h>
#include <hip/hip_bf16.h>

#define Bc   4
#define Pc   12
#define Nc   4096
#define Hc   64
#define TDc  128
#define Ec   65536
#define BPc  48
#define NHc  (Nc*Hc)      // 262144
#define ROWS (BPc*Nc)     // 196608
#define EPSc 1e-5f

typedef float f32x4 __attribute__((ext_vector_type(4)));
typedef short s16x4 __attribute__((ext_vector_type(4)));

__device__ inline short f2bf(float f) {
    union { float f; unsigned u; } v; v.f = f;
    unsigned r = v.u + 0x7FFFu + ((v.u >> 16) & 1u);
    return (short)(r >> 16);
}
__device__ inline s16x4 f2bf4(f32x4 v) {
    s16x4 o;
    o.x = f2bf(v.x); o.y = f2bf(v.y); o.z = f2bf(v.z); o.w = f2bf(v.w);
    return o;
}

// ---------------- time projection: t[b,h] = MLP(time[b,:]) ----------------
__global__ void k_tproj(const float* __restrict__ timev,
                        const float* __restrict__ w1, const float* __restrict__ b1,
                        const float* __restrict__ w2, const float* __restrict__ b2,
                        float* __restrict__ t_out) {
    __shared__ float s_time[Bc * TDc];
    __shared__ float s_hid[Bc * Hc];
    int t = threadIdx.x;
    for (int i = t; i < Bc * TDc; i += 256) s_time[i] = timev[i];
    __syncthreads();
    int b = t >> 6, j = t & 63;
    float acc = b1[j];
    for (int k = 0; k < TDc; ++k) acc = fmaf(s_time[b * TDc + k], w1[j * TDc + k], acc);
    s_hid[b * Hc + j] = fmaxf(acc, 0.f);
    __syncthreads();
    float acc2 = b2[j];
    for (int k = 0; k < Hc; ++k) acc2 = fmaf(s_hid[b * Hc + k], w2[j * Hc + k], acc2);
    t_out[b * Hc + j] = acc2;
}

// ---------------- degree count ----------------
__global__ void k_deg(const int* __restrict__ col, int* __restrict__ deg) {
    int e = blockIdx.x * 256 + threadIdx.x;
    atomicAdd(&deg[col[e]], 1);
}

// ---------------- exclusive scan over 4096 degrees + dis = deg^-1/2 ----------------
__global__ __launch_bounds__(1024) void k_scan(const int* __restrict__ deg,
                                               int* __restrict__ offs,
                                               int* __restrict__ cursor,
                                               float* __restrict__ dis) {
    __shared__ int part[1024];
    int t = threadIdx.x;
    int d0 = deg[t * 4], d1 = deg[t * 4 + 1], d2 = deg[t * 4 + 2], d3 = deg[t * 4 + 3];
    part[t] = d0 + d1 + d2 + d3;
    __syncthreads();
    for (int off = 1; off < 1024; off <<= 1) {
        int v = (t >= off) ? part[t - off] : 0;
        __syncthreads();
        part[t] += v;
        __syncthreads();
    }
    int base = (t ? part[t - 1] : 0);
    offs[t * 4]     = base;
    offs[t * 4 + 1] = base + d0;
    offs[t * 4 + 2] = base + d0 + d1;
    offs[t * 4 + 3] = base + d0 + d1 + d2;
    if (t == 1023) offs[4096] = part[1023];
    cursor[t * 4]     = base;
    cursor[t * 4 + 1] = base + d0;
    cursor[t * 4 + 2] = base + d0 + d1;
    cursor[t * 4 + 3] = base + d0 + d1 + d2;
    dis[t * 4]     = d0 > 0 ? rsqrtf((float)d0) : 0.f;
    dis[t * 4 + 1] = d1 > 0 ? rsqrtf((float)d1) : 0.f;
    dis[t * 4 + 2] = d2 > 0 ? rsqrtf((float)d2) : 0.f;
    dis[t * 4 + 3] = d3 > 0 ? rsqrtf((float)d3) : 0.f;
}

// ---------------- CSR fill ----------------
__global__ void k_fill(const int* __restrict__ ei, int* __restrict__ cursor,
                       const float* __restrict__ dis,
                       int* __restrict__ csr_src, float* __restrict__ csr_w) {
    int e = blockIdx.x * 256 + threadIdx.x;
    int r = ei[e], c = ei[Ec + e];
    int pos = atomicAdd(&cursor[c], 1);
    csr_src[pos] = r;
    csr_w[pos] = dis[r] * dis[c];
}

// ---------------- g1 = gather(gnw), g2 = gather(gnb) ----------------
__global__ __launch_bounds__(128) void k_gw(const int* __restrict__ offs,
                                            const int* __restrict__ csr_src,
                                            const float* __restrict__ csr_w,
                                            const float* __restrict__ gnw,
                                            const float* __restrict__ gnb,
                                            float* __restrict__ g1, float* __restrict__ g2) {
    int n = blockIdx.x;
    int wave = threadIdx.x >> 6, lane = threadIdx.x & 63;
    const float* src = wave ? gnb : gnw;
    float* dst = wave ? g2 : g1;
    int s0 = offs[n], s1 = offs[n + 1];
    float acc = 0.f;
    for (int i = s0; i < s1; ++i) acc = fmaf(csr_w[i], src[csr_src[i] * Hc + lane], acc);
    dst[n * Hc + lane] = acc;
}

// ---------------- MFMA cond-MLP: A = (x + mlp(cond)) * gnw; LN1 stats ----------------
__global__ __launch_bounds__(256) void k_mlp(const float* __restrict__ cond,
                                             const float* __restrict__ x,
                                             const float* __restrict__ w1, const float* __restrict__ b1,
                                             const float* __restrict__ w2, const float* __restrict__ b2,
                                             const float* __restrict__ gnw,
                                             float* __restrict__ Aout, float* __restrict__ part1) {
    __shared__ __align__(16) short s_h[4][16][72];   // per-wave 16 rows x 64 feats (pad 72)
    int lane = threadIdx.x & 63;
    int wv   = threadIdx.x >> 6;
    int r = lane & 15, g = lane >> 4;

    s16x4 a1[4][4], a2[4][4];
    f32x4 b1q[4], b2q[4];
    #pragma unroll
    for (int t = 0; t < 4; ++t) {
        #pragma unroll
        for (int kk = 0; kk < 4; ++kk) {
            a1[t][kk] = f2bf4(*(const f32x4*)(w1 + (16 * t + r) * Hc + kk * 16 + 4 * g));
            a2[t][kk] = f2bf4(*(const f32x4*)(w2 + (16 * t + r) * Hc + kk * 16 + 4 * g));
        }
        b1q[t] = *(const f32x4*)(b1 + 16 * t + 4 * g);
        b2q[t] = *(const f32x4*)(b2 + 16 * t + 4 * g);
    }

    float s = 0.f, ss = 0.f;
    int blockRow = blockIdx.x * 256;
    #pragma unroll
    for (int c = 0; c < 4; ++c) {
        int row = blockRow + wv * 64 + c * 16 + r;
        // layer 1
        s16x4 bc[4];
        #pragma unroll
        for (int kk = 0; kk < 4; ++kk)
            bc[kk] = f2bf4(*(const f32x4*)(cond + (size_t)row * Hc + kk * 16 + 4 * g));
        #pragma unroll
        for (int t = 0; t < 4; ++t) {
            f32x4 acc = {0.f, 0.f, 0.f, 0.f};
            #pragma unroll
            for (int kk = 0; kk < 4; ++kk)
                acc = __builtin_amdgcn_mfma_f32_16x16x16bf16_1k(a1[t][kk], bc[kk], acc, 0, 0, 0);
            acc += b1q[t];
            f32x4 h;
            h.x = fmaxf(acc.x, 0.f); h.y = fmaxf(acc.y, 0.f);
            h.z = fmaxf(acc.z, 0.f); h.w = fmaxf(acc.w, 0.f);
            *(s16x4*)&s_h[wv][r][16 * t + 4 * g] = f2bf4(h);   // hid[r][j..j+3]
        }
        __syncthreads();
        // layer 2
        s16x4 hB[4];
        #pragma unroll
        for (int kk = 0; kk < 4; ++kk)
            hB[kk] = *(const s16x4*)&s_h[wv][r][16 * kk + 4 * g];
        #pragma unroll
        for (int t = 0; t < 4; ++t) {
            f32x4 acc = {0.f, 0.f, 0.f, 0.f};
            #pragma unroll
            for (int kk = 0; kk < 4; ++kk)
                acc = __builtin_amdgcn_mfma_f32_16x16x16bf16_1k(a2[t][kk], hB[kk], acc, 0, 0, 0);
            f32x4 x4 = *(const f32x4*)(x + (size_t)row * Hc + 16 * t + 4 * g);
            f32x4 o = acc + b2q[t] + x4;
            s  += o.x + o.y + o.z + o.w;
            ss += o.x * o.x + o.y * o.y + o.z * o.z + o.w * o.w;
            int n = row & (Nc - 1);
            f32x4 gw4 = *(const f32x4*)(gnw + n * Hc + 16 * t + 4 * g);
            *(f32x4*)(Aout + (size_t)row * Hc + 16 * t + 4 * g) = o * gw4;
        }
        __syncthreads();
    }
    for (int off = 32; off; off >>= 1) { s += __shfl_down(s, off); ss += __shfl_down(ss, off); }
    if (lane == 0) {
        int bp  = blockIdx.x >> 4;             // 16 blocks per bp
        int idx = (blockIdx.x & 15) * 4 + wv;  // 0..63
        part1[(bp * 64 + idx) * 2]     = s;
        part1[(bp * 64 + idx) * 2 + 1] = ss;
    }
}

// ---------------- finalize LN stats: mu, rsqrt(var+eps) per bp ----------------
__global__ __launch_bounds__(256) void k_finalize(const float* __restrict__ part, int cnt,
                                                  float* __restrict__ murs) {
    int bp = blockIdx.x;
    float s = 0.f, ss = 0.f;
    for (int i = threadIdx.x; i < cnt; i += 256) {
        s  += part[(bp * cnt + i) * 2];
        ss += part[(bp * cnt + i) * 2 + 1];
    }
    __shared__ float ls[4], lss[4];
    for (int off = 32; off; off >>= 1) { s += __shfl_down(s, off); ss += __shfl_down(ss, off); }
    int w = threadIdx.x >> 6, l = threadIdx.x & 63;
    if (l == 0) { ls[w] = s; lss[w] = ss; }
    __syncthreads();
    if (threadIdx.x == 0) {
        s  = ls[0] + ls[1] + ls[2] + ls[3];
        ss = lss[0] + lss[1] + lss[2] + lss[3];
        float mu = s / (float)NHc;
        float var = ss / (float)NHc - mu * mu;
        murs[bp * 2]     = mu;
        murs[bp * 2 + 1] = rsqrtf(var + EPSc);
    }
}

// ---------------- LGConv gather (normalized on the fly) + add t; LN2 stats ----------------
// 1-D grid, XCD-pinned: all blocks of a given bp land on XCD bp%8, nchunk-major
// so each XCD streams one 1 MB bp-slice at a time (fits 4 MB L2).
__global__ __launch_bounds__(256) void k_gather(const int* __restrict__ offs,
                                                const int* __restrict__ csr_src,
                                                const float* __restrict__ csr_w,
                                                const float* __restrict__ Ain,
                                                const float* __restrict__ g1,
                                                const float* __restrict__ g2,
                                                const float* __restrict__ murs,
                                                const float* __restrict__ t_in,
                                                float* __restrict__ h2,
                                                float* __restrict__ part2) {
    int bid = blockIdx.x;
    int xcd    = bid & 7;
    int t      = bid >> 3;
    int bpb    = t >> 10;          // bp / 8
    int nchunk = t & 1023;         // 0..1023
    int bp = bpb * 8 + xcd;        // 0..47, pinned to XCD bp%8
    int wv   = threadIdx.x >> 6;
    int lane = threadIdx.x & 63;
    int n = nchunk * 4 + wv;
    int b = bp / Pc;

    const float* base = Ain + (size_t)bp * NHc;
    int s0 = offs[n], s1 = offs[n + 1];

    float a0 = 0.f, a1 = 0.f, a2 = 0.f, a3 = 0.f;
    float a4 = 0.f, a5 = 0.f, a6 = 0.f, a7 = 0.f;
    for (int c0 = s0; c0 < s1; c0 += 64) {
        int rem = s1 - c0;
        int m = rem < 64 ? rem : 64;
        int srcl = 0; float wl = 0.f;
        if (lane < m) { srcl = csr_src[c0 + lane]; wl = csr_w[c0 + lane]; }
        int j = 0;
        for (; j + 8 <= m; j += 8) {
            int   i0 = __shfl(srcl, j),     i1 = __shfl(srcl, j + 1);
            int   i2 = __shfl(srcl, j + 2), i3 = __shfl(srcl, j + 3);
            int   i4 = __shfl(srcl, j + 4), i5 = __shfl(srcl, j + 5);
            int   i6 = __shfl(srcl, j + 6), i7 = __shfl(srcl, j + 7);
            float w0 = __shfl(wl, j),     w1 = __shfl(wl, j + 1);
            float w2 = __shfl(wl, j + 2), w3 = __shfl(wl, j + 3);
            float w4 = __shfl(wl, j + 4), w5 = __shfl(wl, j + 5);
            float w6 = __shfl(wl, j + 6), w7 = __shfl(wl, j + 7);
            float v0 = base[(size_t)i0 * Hc + lane];
            float v1 = base[(size_t)i1 * Hc + lane];
            float v2 = base[(size_t)i2 * Hc + lane];
            float v3 = base[(size_t)i3 * Hc + lane];
            float v4 = base[(size_t)i4 * Hc + lane];
            float v5 = base[(size_t)i5 * Hc + lane];
            float v6 = base[(size_t)i6 * Hc + lane];
            float v7 = base[(size_t)i7 * Hc + lane];
            a0 = fmaf(w0, v0, a0); a1 = fmaf(w1, v1, a1);
            a2 = fmaf(w2, v2, a2); a3 = fmaf(w3, v3, a3);
            a4 = fmaf(w4, v4, a4); a5 = fmaf(w5, v5, a5);
            a6 = fmaf(w6, v6, a6); a7 = fmaf(w7, v7, a7);
        }
        for (; j + 4 <= m; j += 4) {
            int   i0 = __shfl(srcl, j),     i1 = __shfl(srcl, j + 1);
            int   i2 = __shfl(srcl, j + 2), i3 = __shfl(srcl, j + 3);
            float w0 = __shfl(wl, j),     w1 = __shfl(wl, j + 1);
            float w2 = __shfl(wl, j + 2), w3 = __shfl(wl, j + 3);
            float v0 = base[(size_t)i0 * Hc + lane];
            float v1 = base[(size_t)i1 * Hc + lane];
            float v2 = base[(size_t)i2 * Hc + lane];
            float v3 = base[(size_t)i3 * Hc + lane];
            a0 = fmaf(w0, v0, a0); a1 = fmaf(w1, v1, a1);
            a2 = fmaf(w2, v2, a2); a3 = fmaf(w3, v3, a3);
        }
        for (; j < m; ++j) {
            int   i0 = __shfl(srcl, j);
            float w0 = __shfl(wl, j);
            a0 = fmaf(w0, base[(size_t)i0 * Hc + lane], a0);
        }
    }
    float acc = ((a0 + a1) + (a2 + a3)) + ((a4 + a5) + (a6 + a7));

    float mu = murs[bp * 2], rs = murs[bp * 2 + 1];
    float val = rs * (acc - mu * g1[n * Hc + lane]) + g2[n * Hc + lane] + t_in[b * Hc + lane];
    h2[(size_t)bp * NHc + n * Hc + lane] = val;
    float s = val, ss = val * val;
    for (int off = 32; off; off >>= 1) { s += __shfl_down(s, off); ss += __shfl_down(ss, off); }
    if (lane == 0) {
        part2[((size_t)bp * Nc + n) * 2]     = s;
        part2[((size_t)bp * Nc + n) * 2 + 1] = ss;
    }
}

// ---------------- apply LN2 + 1x1 conv over P (h2 may alias out!) ----------------
__global__ __launch_bounds__(256) void k_conv(const float* h2,
                                              const float* __restrict__ murs,
                                              const float* __restrict__ tnw, const float* __restrict__ tnb,
                                              const float* __restrict__ cw, const float* __restrict__ cb,
                                              float* out) {
    int tid = blockIdx.x * 256 + threadIdx.x;  // B * NHc/4 threads
    int b  = tid >> 16;           // / (NHc/4)
    int i4 = tid & 65535;
    size_t e0 = (size_t)i4 * 4;
    float4 w4 = *(const float4*)(tnw + e0);
    float4 b4 = *(const float4*)(tnb + e0);
    float v[Pc][4];
    #pragma unroll
    for (int p = 0; p < Pc; ++p) {
        int bp = b * Pc + p;
        float mu = murs[bp * 2], rs = murs[bp * 2 + 1];
        float4 h = *(const float4*)(h2 + (size_t)bp * NHc + e0);
        v[p][0] = (h.x - mu) * rs * w4.x + b4.x;
        v[p][1] = (h.y - mu) * rs * w4.y + b4.y;
        v[p][2] = (h.z - mu) * rs * w4.z + b4.z;
        v[p][3] = (h.w - mu) * rs * w4.w + b4.w;
    }
    #pragma unroll
    for (int q = 0; q < Pc; ++q) {
        float cbq = cb[q];
        float o0 = cbq, o1 = cbq, o2 = cbq, o3 = cbq;
        #pragma unroll
        for (int p = 0; p < Pc; ++p) {
            float wqp = cw[q * Pc + p];
            o0 = fmaf(v[p][0], wqp, o0);
            o1 = fmaf(v[p][1], wqp, o1);
            o2 = fmaf(v[p][2], wqp, o2);
            o3 = fmaf(v[p][3], wqp, o3);
        }
        float4 o = {o0, o1, o2, o3};
        *(float4*)(out + (size_t)(b * Pc + q) * NHc + e0) = o;
    }
}

extern "C" void kernel_launch(void* const* d_in, const int* in_sizes, int n_in,
                              void* d_out, int out_size, void* d_ws, size_t ws_size,
                              hipStream_t stream) {
    (void)in_sizes; (void)n_in; (void)out_size; (void)ws_size;
    const float* x     = (const float*)d_in[0];
    const int*   ei    = (const int*)  d_in[1];
    const float* timev = (const float*)d_in[2];
    const float* cond  = (const float*)d_in[3];
    const float* tp_w1 = (const float*)d_in[4];
    const float* tp_b1 = (const float*)d_in[5];
    const float* tp_w2 = (const float*)d_in[6];
    const float* tp_b2 = (const float*)d_in[7];
    const float* cp_w1 = (const float*)d_in[8];
    const float* cp_b1 = (const float*)d_in[9];
    const float* cp_w2 = (const float*)d_in[10];
    const float* cp_b2 = (const float*)d_in[11];
    const float* gn_w  = (const float*)d_in[12];
    const float* gn_b  = (const float*)d_in[13];
    const float* tn_w  = (const float*)d_in[14];
    const float* tn_b  = (const float*)d_in[15];
    const float* cw    = (const float*)d_in[16];
    const float* cb    = (const float*)d_in[17];
    float* out = (float*)d_out;

    char* w = (char*)d_ws;
    size_t off = 0;
    auto alloc = [&](size_t bytes) {
        void* p = w + off;
        off = (off + bytes + 255) & ~(size_t)255;
        return p;
    };
    float* bufA    = (float*)alloc((size_t)ROWS * Hc * sizeof(float)); // A = h1*gnw
    float* part1   = (float*)alloc((size_t)BPc * 64 * 2 * 4);
    float* part2   = (float*)alloc((size_t)BPc * Nc * 2 * 4);
    float* murs1   = (float*)alloc(96 * 4);
    float* murs2   = (float*)alloc(96 * 4);
    float* t_ws    = (float*)alloc(256 * 4);
    float* dis     = (float*)alloc(Nc * 4);
    float* csr_w   = (float*)alloc(Ec * 4);
    float* g1      = (float*)alloc((size_t)NHc * 4);
    float* g2      = (float*)alloc((size_t)NHc * 4);
    int*   deg     = (int*)alloc(Nc * 4);
    int*   offs    = (int*)alloc((Nc + 1) * 4);
    int*   cursor  = (int*)alloc(Nc * 4);
    int*   csr_src = (int*)alloc(Ec * 4);
    float* h2 = out;  // gather output lives in d_out; k_conv is alias-safe

    hipMemsetAsync(deg, 0, Nc * sizeof(int), stream);
    k_tproj<<<1, 256, 0, stream>>>(timev, tp_w1, tp_b1, tp_w2, tp_b2, t_ws);
    k_deg<<<Ec / 256, 256, 0, stream>>>(ei + Ec, deg);
    k_scan<<<1, 1024, 0, stream>>>(deg, offs, cursor, dis);
    k_fill<<<Ec / 256, 256, 0, stream>>>(ei, cursor, dis, csr_src, csr_w);
    k_gw<<<Nc, 128, 0, stream>>>(offs, csr_src, csr_w, gn_w, gn_b, g1, g2);
    k_mlp<<<ROWS / 256, 256, 0, stream>>>(cond, x, cp_w1, cp_b1, cp_w2, cp_b2, gn_w, bufA, part1);
    k_finalize<<<BPc, 256, 0, stream>>>(part1, 64, murs1);
    k_gather<<<BPc * 1024, 256, 0, stream>>>(offs, csr_src, csr_w, bufA, g1, g2,
                                             murs1, t_ws, h2, part2);
    k_finalize<<<BPc, 256, 0, stream>>>(part2, Nc, murs2);
    k_conv<<<(Bc * NHc / 4) / 256, 256, 0, stream>>>(h2, murs2, tn_w, tn_b, cw, cb, out);
}

// Round 4
// 182.956 us; speedup vs baseline: 2.7286x; 1.1210x over previous
//
#include <hip/hip_runtime.h>
#include <hip/hip_bf16.h>

#define Bc   4
#define Pc   12
#define Nc   4096
#define Hc   64
#define TDc  128
#define Ec   65536
#define BPc  48
#define NHc  (Nc*Hc)      // 262144
#define ROWS (BPc*Nc)     // 196608
#define EPSc 1e-5f

typedef float f32x4 __attribute__((ext_vector_type(4)));
typedef short s16x4 __attribute__((ext_vector_type(4)));

__device__ inline short f2bf(float f) {
    union { float f; unsigned u; } v; v.f = f;
    unsigned r = v.u + 0x7FFFu + ((v.u >> 16) & 1u);
    return (short)(r >> 16);
}
__device__ inline s16x4 f2bf4(f32x4 v) {
    s16x4 o;
    o.x = f2bf(v.x); o.y = f2bf(v.y); o.z = f2bf(v.z); o.w = f2bf(v.w);
    return o;
}

// ---------------- time projection: t[b,h] = MLP(time[b,:]) ----------------
__global__ void k_tproj(const float* __restrict__ timev,
                        const float* __restrict__ w1, const float* __restrict__ b1,
                        const float* __restrict__ w2, const float* __restrict__ b2,
                        float* __restrict__ t_out) {
    __shared__ float s_time[Bc * TDc];
    __shared__ float s_hid[Bc * Hc];
    int t = threadIdx.x;
    for (int i = t; i < Bc * TDc; i += 256) s_time[i] = timev[i];
    __syncthreads();
    int b = t >> 6, j = t & 63;
    float acc = b1[j];
    for (int k = 0; k < TDc; ++k) acc = fmaf(s_time[b * TDc + k], w1[j * TDc + k], acc);
    s_hid[b * Hc + j] = fmaxf(acc, 0.f);
    __syncthreads();
    float acc2 = b2[j];
    for (int k = 0; k < Hc; ++k) acc2 = fmaf(s_hid[b * Hc + k], w2[j * Hc + k], acc2);
    t_out[b * Hc + j] = acc2;
}

// ---------------- degree count ----------------
__global__ void k_deg(const int* __restrict__ col, int* __restrict__ deg) {
    int e = blockIdx.x * 256 + threadIdx.x;
    atomicAdd(&deg[col[e]], 1);
}

// ---------------- exclusive scan over 4096 degrees + dis = deg^-1/2 ----------------
__global__ __launch_bounds__(1024) void k_scan(const int* __restrict__ deg,
                                               int* __restrict__ offs,
                                               int* __restrict__ cursor,
                                               float* __restrict__ dis) {
    __shared__ int part[1024];
    int t = threadIdx.x;
    int d0 = deg[t * 4], d1 = deg[t * 4 + 1], d2 = deg[t * 4 + 2], d3 = deg[t * 4 + 3];
    part[t] = d0 + d1 + d2 + d3;
    __syncthreads();
    for (int off = 1; off < 1024; off <<= 1) {
        int v = (t >= off) ? part[t - off] : 0;
        __syncthreads();
        part[t] += v;
        __syncthreads();
    }
    int base = (t ? part[t - 1] : 0);
    offs[t * 4]     = base;
    offs[t * 4 + 1] = base + d0;
    offs[t * 4 + 2] = base + d0 + d1;
    offs[t * 4 + 3] = base + d0 + d1 + d2;
    if (t == 1023) offs[4096] = part[1023];
    cursor[t * 4]     = base;
    cursor[t * 4 + 1] = base + d0;
    cursor[t * 4 + 2] = base + d0 + d1;
    cursor[t * 4 + 3] = base + d0 + d1 + d2;
    dis[t * 4]     = d0 > 0 ? rsqrtf((float)d0) : 0.f;
    dis[t * 4 + 1] = d1 > 0 ? rsqrtf((float)d1) : 0.f;
    dis[t * 4 + 2] = d2 > 0 ? rsqrtf((float)d2) : 0.f;
    dis[t * 4 + 3] = d3 > 0 ? rsqrtf((float)d3) : 0.f;
}

// ---------------- CSR fill: csr2 = {src*Hc, bits(w)} ----------------
__global__ void k_fill(const int* __restrict__ ei, int* __restrict__ cursor,
                       const float* __restrict__ dis,
                       int2* __restrict__ csr2) {
    int e = blockIdx.x * 256 + threadIdx.x;
    int r = ei[e], c = ei[Ec + e];
    int pos = atomicAdd(&cursor[c], 1);
    int2 v;
    v.x = r * Hc;
    v.y = __float_as_int(dis[r] * dis[c]);
    csr2[pos] = v;
}

// ---------------- g1 = gather(gnw), g2 = gather(gnb) ----------------
__global__ __launch_bounds__(128) void k_gw(const int* __restrict__ offs,
                                            const int2* __restrict__ csr2,
                                            const float* __restrict__ gnw,
                                            const float* __restrict__ gnb,
                                            float* __restrict__ g1, float* __restrict__ g2) {
    int n = blockIdx.x;
    int wave = threadIdx.x >> 6, lane = threadIdx.x & 63;
    const float* src = wave ? gnb : gnw;
    float* dst = wave ? g2 : g1;
    int s0 = __builtin_amdgcn_readfirstlane(offs[n]);
    int s1 = __builtin_amdgcn_readfirstlane(offs[n + 1]);
    float a0 = 0.f, a1 = 0.f, a2 = 0.f, a3 = 0.f;
    int i = s0;
    for (; i + 4 <= s1; i += 4) {
        int2 e0 = csr2[i], e1 = csr2[i + 1], e2 = csr2[i + 2], e3 = csr2[i + 3];
        a0 = fmaf(__int_as_float(e0.y), src[e0.x + lane], a0);
        a1 = fmaf(__int_as_float(e1.y), src[e1.x + lane], a1);
        a2 = fmaf(__int_as_float(e2.y), src[e2.x + lane], a2);
        a3 = fmaf(__int_as_float(e3.y), src[e3.x + lane], a3);
    }
    for (; i < s1; ++i) {
        int2 e = csr2[i];
        a0 = fmaf(__int_as_float(e.y), src[e.x + lane], a0);
    }
    dst[n * Hc + lane] = (a0 + a1) + (a2 + a3);
}

// ---------------- MFMA cond-MLP: A = (x + mlp(cond)) * gnw; LN1 stats ----------------
// Key fact: layer-1 D-fragment (row r, feat 16t+4g+i) == layer-2 B-fragment
// (col r, k 16kk+4g+i) for the SAME lane -> no LDS, no barriers needed.
__global__ __launch_bounds__(256) void k_mlp(const float* __restrict__ cond,
                                             const float* __restrict__ x,
                                             const float* __restrict__ w1, const float* __restrict__ b1,
                                             const float* __restrict__ w2, const float* __restrict__ b2,
                                             const float* __restrict__ gnw,
                                             float* __restrict__ Aout, float* __restrict__ part1) {
    int lane = threadIdx.x & 63;
    int wv   = threadIdx.x >> 6;
    int r = lane & 15, g = lane >> 4;

    s16x4 a1[4][4], a2[4][4];
    f32x4 b1q[4], b2q[4];
    #pragma unroll
    for (int t = 0; t < 4; ++t) {
        #pragma unroll
        for (int kk = 0; kk < 4; ++kk) {
            a1[t][kk] = f2bf4(*(const f32x4*)(w1 + (16 * t + r) * Hc + kk * 16 + 4 * g));
            a2[t][kk] = f2bf4(*(const f32x4*)(w2 + (16 * t + r) * Hc + kk * 16 + 4 * g));
        }
        b1q[t] = *(const f32x4*)(b1 + 16 * t + 4 * g);
        b2q[t] = *(const f32x4*)(b2 + 16 * t + 4 * g);
    }

    float s = 0.f, ss = 0.f;
    int blockRow = blockIdx.x * 256;
    #pragma unroll
    for (int c = 0; c < 4; ++c) {
        int row = blockRow + wv * 64 + c * 16 + r;
        // layer 1
        s16x4 bc[4];
        #pragma unroll
        for (int kk = 0; kk < 4; ++kk)
            bc[kk] = f2bf4(*(const f32x4*)(cond + (size_t)row * Hc + kk * 16 + 4 * g));
        s16x4 hB[4];
        #pragma unroll
        for (int t = 0; t < 4; ++t) {
            f32x4 acc = {0.f, 0.f, 0.f, 0.f};
            #pragma unroll
            for (int kk = 0; kk < 4; ++kk)
                acc = __builtin_amdgcn_mfma_f32_16x16x16bf16_1k(a1[t][kk], bc[kk], acc, 0, 0, 0);
            acc += b1q[t];
            f32x4 h;
            h.x = fmaxf(acc.x, 0.f); h.y = fmaxf(acc.y, 0.f);
            h.z = fmaxf(acc.z, 0.f); h.w = fmaxf(acc.w, 0.f);
            hB[t] = f2bf4(h);
        }
        // layer 2
        #pragma unroll
        for (int t = 0; t < 4; ++t) {
            f32x4 acc = {0.f, 0.f, 0.f, 0.f};
            #pragma unroll
            for (int kk = 0; kk < 4; ++kk)
                acc = __builtin_amdgcn_mfma_f32_16x16x16bf16_1k(a2[t][kk], hB[kk], acc, 0, 0, 0);
            f32x4 x4 = *(const f32x4*)(x + (size_t)row * Hc + 16 * t + 4 * g);
            f32x4 o = acc + b2q[t] + x4;
            s  += o.x + o.y + o.z + o.w;
            ss += o.x * o.x + o.y * o.y + o.z * o.z + o.w * o.w;
            int n = row & (Nc - 1);
            f32x4 gw4 = *(const f32x4*)(gnw + n * Hc + 16 * t + 4 * g);
            *(f32x4*)(Aout + (size_t)row * Hc + 16 * t + 4 * g) = o * gw4;
        }
    }
    for (int off = 32; off; off >>= 1) { s += __shfl_down(s, off); ss += __shfl_down(ss, off); }
    if (lane == 0) {
        int bp  = blockIdx.x >> 4;             // 16 blocks per bp
        int idx = (blockIdx.x & 15) * 4 + wv;  // 0..63
        part1[(bp * 64 + idx) * 2]     = s;
        part1[(bp * 64 + idx) * 2 + 1] = ss;
    }
}

// ---------------- finalize LN stats: mu, rsqrt(var+eps) per bp ----------------
__global__ __launch_bounds__(256) void k_finalize(const float* __restrict__ part, int cnt,
                                                  float* __restrict__ murs) {
    int bp = blockIdx.x;
    float s = 0.f, ss = 0.f;
    for (int i = threadIdx.x; i < cnt; i += 256) {
        s  += part[(bp * cnt + i) * 2];
        ss += part[(bp * cnt + i) * 2 + 1];
    }
    __shared__ float ls[4], lss[4];
    for (int off = 32; off; off >>= 1) { s += __shfl_down(s, off); ss += __shfl_down(ss, off); }
    int w = threadIdx.x >> 6, l = threadIdx.x & 63;
    if (l == 0) { ls[w] = s; lss[w] = ss; }
    __syncthreads();
    if (threadIdx.x == 0) {
        s  = ls[0] + ls[1] + ls[2] + ls[3];
        ss = lss[0] + lss[1] + lss[2] + lss[3];
        float mu = s / (float)NHc;
        float var = ss / (float)NHc - mu * mu;
        murs[bp * 2]     = mu;
        murs[bp * 2 + 1] = rsqrtf(var + EPSc);
    }
}

// ---------------- LGConv gather (scalar-pipe edge stream) + add t; LN2 stats ----------------
// 1-D grid, XCD-pinned: all blocks of a given bp land on XCD bp%8, nchunk-major
// so each XCD streams one 1 MB bp-slice at a time (fits 4 MB L2).
// Edge list per (n, wave) is wave-uniform -> readfirstlane forces SGPR bounds so
// csr2[idx] scalarizes to s_load (SALU/SMEM in parallel with VALU fma stream).
__global__ __launch_bounds__(256) void k_gather(const int* __restrict__ offs,
                                                const int2* __restrict__ csr2,
                                                const float* __restrict__ Ain,
                                                const float* __restrict__ g1,
                                                const float* __restrict__ g2,
                                                const float* __restrict__ murs,
                                                const float* __restrict__ t_in,
                                                float* __restrict__ h2,
                                                float* __restrict__ part2) {
    int bid = blockIdx.x;
    int xcd    = bid & 7;
    int t      = bid >> 3;
    int bpb    = t >> 10;          // bp / 8
    int nchunk = t & 1023;         // 0..1023
    int bp = bpb * 8 + xcd;        // 0..47, pinned to XCD bp%8
    int wv   = threadIdx.x >> 6;
    int lane = threadIdx.x & 63;
    int n = __builtin_amdgcn_readfirstlane(nchunk * 4 + wv);
    int b = bp / Pc;

    const float* base = Ain + (size_t)bp * NHc;
    int s0 = __builtin_amdgcn_readfirstlane(offs[n]);
    int s1 = __builtin_amdgcn_readfirstlane(offs[n + 1]);

    float a0 = 0.f, a1 = 0.f, a2 = 0.f, a3 = 0.f;
    float a4 = 0.f, a5 = 0.f, a6 = 0.f, a7 = 0.f;
    int idx = s0;
    for (; idx + 8 <= s1; idx += 8) {
        int2 e0 = csr2[idx],     e1 = csr2[idx + 1];
        int2 e2 = csr2[idx + 2], e3 = csr2[idx + 3];
        int2 e4 = csr2[idx + 4], e5 = csr2[idx + 5];
        int2 e6 = csr2[idx + 6], e7 = csr2[idx + 7];
        float v0 = base[e0.x + lane];
        float v1 = base[e1.x + lane];
        float v2 = base[e2.x + lane];
        float v3 = base[e3.x + lane];
        float v4 = base[e4.x + lane];
        float v5 = base[e5.x + lane];
        float v6 = base[e6.x + lane];
        float v7 = base[e7.x + lane];
        a0 = fmaf(__int_as_float(e0.y), v0, a0);
        a1 = fmaf(__int_as_float(e1.y), v1, a1);
        a2 = fmaf(__int_as_float(e2.y), v2, a2);
        a3 = fmaf(__int_as_float(e3.y), v3, a3);
        a4 = fmaf(__int_as_float(e4.y), v4, a4);
        a5 = fmaf(__int_as_float(e5.y), v5, a5);
        a6 = fmaf(__int_as_float(e6.y), v6, a6);
        a7 = fmaf(__int_as_float(e7.y), v7, a7);
    }
    for (; idx < s1; ++idx) {
        int2 e = csr2[idx];
        a0 = fmaf(__int_as_float(e.y), base[e.x + lane], a0);
    }
    float acc = ((a0 + a1) + (a2 + a3)) + ((a4 + a5) + (a6 + a7));

    float mu = murs[bp * 2], rs = murs[bp * 2 + 1];
    float val = rs * (acc - mu * g1[n * Hc + lane]) + g2[n * Hc + lane] + t_in[b * Hc + lane];
    h2[(size_t)bp * NHc + n * Hc + lane] = val;
    float s = val, ss = val * val;
    for (int off = 32; off; off >>= 1) { s += __shfl_down(s, off); ss += __shfl_down(ss, off); }
    if (lane == 0) {
        part2[((size_t)bp * Nc + n) * 2]     = s;
        part2[((size_t)bp * Nc + n) * 2 + 1] = ss;
    }
}

// ---------------- apply LN2 + 1x1 conv over P (h2 may alias out!) ----------------
__global__ __launch_bounds__(256) void k_conv(const float* h2,
                                              const float* __restrict__ murs,
                                              const float* __restrict__ tnw, const float* __restrict__ tnb,
                                              const float* __restrict__ cw, const float* __restrict__ cb,
                                              float* out) {
    int tid = blockIdx.x * 256 + threadIdx.x;  // B * NHc/4 threads
    int b  = tid >> 16;           // / (NHc/4)
    int i4 = tid & 65535;
    size_t e0 = (size_t)i4 * 4;
    float4 w4 = *(const float4*)(tnw + e0);
    float4 b4 = *(const float4*)(tnb + e0);
    float v[Pc][4];
    #pragma unroll
    for (int p = 0; p < Pc; ++p) {
        int bp = b * Pc + p;
        float mu = murs[bp * 2], rs = murs[bp * 2 + 1];
        float4 h = *(const float4*)(h2 + (size_t)bp * NHc + e0);
        v[p][0] = (h.x - mu) * rs * w4.x + b4.x;
        v[p][1] = (h.y - mu) * rs * w4.y + b4.y;
        v[p][2] = (h.z - mu) * rs * w4.z + b4.z;
        v[p][3] = (h.w - mu) * rs * w4.w + b4.w;
    }
    #pragma unroll
    for (int q = 0; q < Pc; ++q) {
        float cbq = cb[q];
        float o0 = cbq, o1 = cbq, o2 = cbq, o3 = cbq;
        #pragma unroll
        for (int p = 0; p < Pc; ++p) {
            float wqp = cw[q * Pc + p];
            o0 = fmaf(v[p][0], wqp, o0);
            o1 = fmaf(v[p][1], wqp, o1);
            o2 = fmaf(v[p][2], wqp, o2);
            o3 = fmaf(v[p][3], wqp, o3);
        }
        float4 o = {o0, o1, o2, o3};
        *(float4*)(out + (size_t)(b * Pc + q) * NHc + e0) = o;
    }
}

extern "C" void kernel_launch(void* const* d_in, const int* in_sizes, int n_in,
                              void* d_out, int out_size, void* d_ws, size_t ws_size,
                              hipStream_t stream) {
    (void)in_sizes; (void)n_in; (void)out_size; (void)ws_size;
    const float* x     = (const float*)d_in[0];
    const int*   ei    = (const int*)  d_in[1];
    const float* timev = (const float*)d_in[2];
    const float* cond  = (const float*)d_in[3];
    const float* tp_w1 = (const float*)d_in[4];
    const float* tp_b1 = (const float*)d_in[5];
    const float* tp_w2 = (const float*)d_in[6];
    const float* tp_b2 = (const float*)d_in[7];
    const float* cp_w1 = (const float*)d_in[8];
    const float* cp_b1 = (const float*)d_in[9];
    const float* cp_w2 = (const float*)d_in[10];
    const float* cp_b2 = (const float*)d_in[11];
    const float* gn_w  = (const float*)d_in[12];
    const float* gn_b  = (const float*)d_in[13];
    const float* tn_w  = (const float*)d_in[14];
    const float* tn_b  = (const float*)d_in[15];
    const float* cw    = (const float*)d_in[16];
    const float* cb    = (const float*)d_in[17];
    float* out = (float*)d_out;

    char* w = (char*)d_ws;
    size_t off = 0;
    auto alloc = [&](size_t bytes) {
        void* p = w + off;
        off = (off + bytes + 255) & ~(size_t)255;
        return p;
    };
    float* bufA    = (float*)alloc((size_t)ROWS * Hc * sizeof(float)); // A = h1*gnw
    float* part1   = (float*)alloc((size_t)BPc * 64 * 2 * 4);
    float* part2   = (float*)alloc((size_t)BPc * Nc * 2 * 4);
    float* murs1   = (float*)alloc(96 * 4);
    float* murs2   = (float*)alloc(96 * 4);
    float* t_ws    = (float*)alloc(256 * 4);
    float* dis     = (float*)alloc(Nc * 4);
    int2*  csr2    = (int2*)alloc((size_t)Ec * 8);
    float* g1      = (float*)alloc((size_t)NHc * 4);
    float* g2      = (float*)alloc((size_t)NHc * 4);
    int*   deg     = (int*)alloc(Nc * 4);
    int*   offs    = (int*)alloc((Nc + 1) * 4);
    int*   cursor  = (int*)alloc(Nc * 4);
    float* h2 = out;  // gather output lives in d_out; k_conv is alias-safe

    hipMemsetAsync(deg, 0, Nc * sizeof(int), stream);
    k_tproj<<<1, 256, 0, stream>>>(timev, tp_w1, tp_b1, tp_w2, tp_b2, t_ws);
    k_deg<<<Ec / 256, 256, 0, stream>>>(ei + Ec, deg);
    k_scan<<<1, 1024, 0, stream>>>(deg, offs, cursor, dis);
    k_fill<<<Ec / 256, 256, 0, stream>>>(ei, cursor, dis, csr2);
    k_gw<<<Nc, 128, 0, stream>>>(offs, csr2, gn_w, gn_b, g1, g2);
    k_mlp<<<ROWS / 256, 256, 0, stream>>>(cond, x, cp_w1, cp_b1, cp_w2, cp_b2, gn_w, bufA, part1);
    k_finalize<<<BPc, 256, 0, stream>>>(part1, 64, murs1);
    k_gather<<<BPc * 1024, 256, 0, stream>>>(offs, csr2, bufA, g1, g2,
                                             murs1, t_ws, h2, part2);
    k_finalize<<<BPc, 256, 0, stream>>>(part2, Nc, murs2);
    k_conv<<<(Bc * NHc / 4) / 256, 256, 0, stream>>>(h2, murs2, tn_w, tn_b, cw, cb, out);
}

// Round 5
// 162.684 us; speedup vs baseline: 3.0686x; 1.1246x over previous
//
#include <hip/hip_runtime.h>
#include <hip/hip_bf16.h>

#define Bc   4
#define Pc   12
#define Nc   4096
#define Hc   64
#define TDc  128
#define Ec   65536
#define BPc  48
#define NHc  (Nc*Hc)      // 262144
#define ROWS (BPc*Nc)     // 196608
#define EPSc 1e-5f

typedef float f32x4 __attribute__((ext_vector_type(4)));
typedef float f32x2 __attribute__((ext_vector_type(2)));
typedef short s16x4 __attribute__((ext_vector_type(4)));

__device__ inline short f2bf(float f) {
    union { float f; unsigned u; } v; v.f = f;
    unsigned r = v.u + 0x7FFFu + ((v.u >> 16) & 1u);
    return (short)(r >> 16);
}
__device__ inline s16x4 f2bf4(f32x4 v) {
    s16x4 o;
    o.x = f2bf(v.x); o.y = f2bf(v.y); o.z = f2bf(v.z); o.w = f2bf(v.w);
    return o;
}

// ---------------- time projection: t[b,h] = MLP(time[b,:]) ----------------
__global__ void k_tproj(const float* __restrict__ timev,
                        const float* __restrict__ w1, const float* __restrict__ b1,
                        const float* __restrict__ w2, const float* __restrict__ b2,
                        float* __restrict__ t_out) {
    __shared__ float s_time[Bc * TDc];
    __shared__ float s_hid[Bc * Hc];
    int t = threadIdx.x;
    for (int i = t; i < Bc * TDc; i += 256) s_time[i] = timev[i];
    __syncthreads();
    int b = t >> 6, j = t & 63;
    float acc = b1[j];
    for (int k = 0; k < TDc; ++k) acc = fmaf(s_time[b * TDc + k], w1[j * TDc + k], acc);
    s_hid[b * Hc + j] = fmaxf(acc, 0.f);
    __syncthreads();
    float acc2 = b2[j];
    for (int k = 0; k < Hc; ++k) acc2 = fmaf(s_hid[b * Hc + k], w2[j * Hc + k], acc2);
    t_out[b * Hc + j] = acc2;
}

// ---------------- degree count ----------------
__global__ void k_deg(const int* __restrict__ col, int* __restrict__ deg) {
    int e = blockIdx.x * 256 + threadIdx.x;
    atomicAdd(&deg[col[e]], 1);
}

// ---------------- exclusive scan over 4096 degrees + dis = deg^-1/2 ----------------
__global__ __launch_bounds__(1024) void k_scan(const int* __restrict__ deg,
                                               int* __restrict__ offs,
                                               int* __restrict__ cursor,
                                               float* __restrict__ dis) {
    __shared__ int part[1024];
    int t = threadIdx.x;
    int d0 = deg[t * 4], d1 = deg[t * 4 + 1], d2 = deg[t * 4 + 2], d3 = deg[t * 4 + 3];
    part[t] = d0 + d1 + d2 + d3;
    __syncthreads();
    for (int off = 1; off < 1024; off <<= 1) {
        int v = (t >= off) ? part[t - off] : 0;
        __syncthreads();
        part[t] += v;
        __syncthreads();
    }
    int base = (t ? part[t - 1] : 0);
    offs[t * 4]     = base;
    offs[t * 4 + 1] = base + d0;
    offs[t * 4 + 2] = base + d0 + d1;
    offs[t * 4 + 3] = base + d0 + d1 + d2;
    if (t == 1023) offs[4096] = part[1023];
    cursor[t * 4]     = base;
    cursor[t * 4 + 1] = base + d0;
    cursor[t * 4 + 2] = base + d0 + d1;
    cursor[t * 4 + 3] = base + d0 + d1 + d2;
    dis[t * 4]     = d0 > 0 ? rsqrtf((float)d0) : 0.f;
    dis[t * 4 + 1] = d1 > 0 ? rsqrtf((float)d1) : 0.f;
    dis[t * 4 + 2] = d2 > 0 ? rsqrtf((float)d2) : 0.f;
    dis[t * 4 + 3] = d3 > 0 ? rsqrtf((float)d3) : 0.f;
}

// ---------------- CSR fill: csr2 = {src*Hc, bits(w)} ----------------
__global__ void k_fill(const int* __restrict__ ei, int* __restrict__ cursor,
                       const float* __restrict__ dis,
                       int2* __restrict__ csr2) {
    int e = blockIdx.x * 256 + threadIdx.x;
    int r = ei[e], c = ei[Ec + e];
    int pos = atomicAdd(&cursor[c], 1);
    int2 v;
    v.x = r * Hc;
    v.y = __float_as_int(dis[r] * dis[c]);
    csr2[pos] = v;
}

// ---------------- g1 = gather(gnw), g2 = gather(gnb) ----------------
__global__ __launch_bounds__(128) void k_gw(const int* __restrict__ offs,
                                            const int2* __restrict__ csr2,
                                            const float* __restrict__ gnw,
                                            const float* __restrict__ gnb,
                                            float* __restrict__ g1, float* __restrict__ g2) {
    int n = blockIdx.x;
    int wave = threadIdx.x >> 6, lane = threadIdx.x & 63;
    const float* src = wave ? gnb : gnw;
    float* dst = wave ? g2 : g1;
    int s0 = __builtin_amdgcn_readfirstlane(offs[n]);
    int s1 = __builtin_amdgcn_readfirstlane(offs[n + 1]);
    float a0 = 0.f, a1 = 0.f, a2 = 0.f, a3 = 0.f;
    int i = s0;
    for (; i + 4 <= s1; i += 4) {
        int2 e0 = csr2[i], e1 = csr2[i + 1], e2 = csr2[i + 2], e3 = csr2[i + 3];
        a0 = fmaf(__int_as_float(e0.y), src[e0.x + lane], a0);
        a1 = fmaf(__int_as_float(e1.y), src[e1.x + lane], a1);
        a2 = fmaf(__int_as_float(e2.y), src[e2.x + lane], a2);
        a3 = fmaf(__int_as_float(e3.y), src[e3.x + lane], a3);
    }
    for (; i < s1; ++i) {
        int2 e = csr2[i];
        a0 = fmaf(__int_as_float(e.y), src[e.x + lane], a0);
    }
    dst[n * Hc + lane] = (a0 + a1) + (a2 + a3);
}

// ---------------- MFMA cond-MLP: A = (x + mlp(cond)) * gnw; LN1 stats ----------------
// Key fact: layer-1 D-fragment (row r, feat 16t+4g+i) == layer-2 B-fragment
// (col r, k 16kk+4g+i) for the SAME lane -> no LDS, no barriers needed.
__global__ __launch_bounds__(256) void k_mlp(const float* __restrict__ cond,
                                             const float* __restrict__ x,
                                             const float* __restrict__ w1, const float* __restrict__ b1,
                                             const float* __restrict__ w2, const float* __restrict__ b2,
                                             const float* __restrict__ gnw,
                                             float* __restrict__ Aout, float* __restrict__ part1) {
    int lane = threadIdx.x & 63;
    int wv   = threadIdx.x >> 6;
    int r = lane & 15, g = lane >> 4;

    s16x4 a1[4][4], a2[4][4];
    f32x4 b1q[4], b2q[4];
    #pragma unroll
    for (int t = 0; t < 4; ++t) {
        #pragma unroll
        for (int kk = 0; kk < 4; ++kk) {
            a1[t][kk] = f2bf4(*(const f32x4*)(w1 + (16 * t + r) * Hc + kk * 16 + 4 * g));
            a2[t][kk] = f2bf4(*(const f32x4*)(w2 + (16 * t + r) * Hc + kk * 16 + 4 * g));
        }
        b1q[t] = *(const f32x4*)(b1 + 16 * t + 4 * g);
        b2q[t] = *(const f32x4*)(b2 + 16 * t + 4 * g);
    }

    float s = 0.f, ss = 0.f;
    int blockRow = blockIdx.x * 256;
    #pragma unroll
    for (int c = 0; c < 4; ++c) {
        int row = blockRow + wv * 64 + c * 16 + r;
        // layer 1
        s16x4 bc[4];
        #pragma unroll
        for (int kk = 0; kk < 4; ++kk)
            bc[kk] = f2bf4(*(const f32x4*)(cond + (size_t)row * Hc + kk * 16 + 4 * g));
        s16x4 hB[4];
        #pragma unroll
        for (int t = 0; t < 4; ++t) {
            f32x4 acc = {0.f, 0.f, 0.f, 0.f};
            #pragma unroll
            for (int kk = 0; kk < 4; ++kk)
                acc = __builtin_amdgcn_mfma_f32_16x16x16bf16_1k(a1[t][kk], bc[kk], acc, 0, 0, 0);
            acc += b1q[t];
            f32x4 h;
            h.x = fmaxf(acc.x, 0.f); h.y = fmaxf(acc.y, 0.f);
            h.z = fmaxf(acc.z, 0.f); h.w = fmaxf(acc.w, 0.f);
            hB[t] = f2bf4(h);
        }
        // layer 2
        #pragma unroll
        for (int t = 0; t < 4; ++t) {
            f32x4 acc = {0.f, 0.f, 0.f, 0.f};
            #pragma unroll
            for (int kk = 0; kk < 4; ++kk)
                acc = __builtin_amdgcn_mfma_f32_16x16x16bf16_1k(a2[t][kk], hB[kk], acc, 0, 0, 0);
            f32x4 x4 = *(const f32x4*)(x + (size_t)row * Hc + 16 * t + 4 * g);
            f32x4 o = acc + b2q[t] + x4;
            s  += o.x + o.y + o.z + o.w;
            ss += o.x * o.x + o.y * o.y + o.z * o.z + o.w * o.w;
            int n = row & (Nc - 1);
            f32x4 gw4 = *(const f32x4*)(gnw + n * Hc + 16 * t + 4 * g);
            *(f32x4*)(Aout + (size_t)row * Hc + 16 * t + 4 * g) = o * gw4;
        }
    }
    for (int off = 32; off; off >>= 1) { s += __shfl_down(s, off); ss += __shfl_down(ss, off); }
    if (lane == 0) {
        int bp  = blockIdx.x >> 4;             // 16 blocks per bp
        int idx = (blockIdx.x & 15) * 4 + wv;  // 0..63
        part1[(bp * 64 + idx) * 2]     = s;
        part1[(bp * 64 + idx) * 2 + 1] = ss;
    }
}

// ---------------- finalize LN stats: mu, rsqrt(var+eps) per bp ----------------
__global__ __launch_bounds__(256) void k_finalize(const float* __restrict__ part, int cnt,
                                                  float* __restrict__ murs) {
    int bp = blockIdx.x;
    float s = 0.f, ss = 0.f;
    for (int i = threadIdx.x; i < cnt; i += 256) {
        s  += part[(bp * cnt + i) * 2];
        ss += part[(bp * cnt + i) * 2 + 1];
    }
    __shared__ float ls[4], lss[4];
    for (int off = 32; off; off >>= 1) { s += __shfl_down(s, off); ss += __shfl_down(ss, off); }
    int w = threadIdx.x >> 6, l = threadIdx.x & 63;
    if (l == 0) { ls[w] = s; lss[w] = ss; }
    __syncthreads();
    if (threadIdx.x == 0) {
        s  = ls[0] + ls[1] + ls[2] + ls[3];
        ss = lss[0] + lss[1] + lss[2] + lss[3];
        float mu = s / (float)NHc;
        float var = ss / (float)NHc - mu * mu;
        murs[bp * 2]     = mu;
        murs[bp * 2 + 1] = rsqrtf(var + EPSc);
    }
}

// ---------------- LGConv gather: 1 n x 2 bp per wave, float2 lanes ----------------
// XCD-pinned balanced: 3 bp-pairs per XCD column (bp = xcd + 8*bpb, pairs of bpb),
// nchunk-major so each XCD streams one 2 MB pair-slice at a time (fits 4 MB L2).
// Lanes 0-31 -> bp0, lanes 32-63 -> bp1; each lane owns 2 features (float2 load:
// one dwordx2 instr fetches 512 B = both rows -> half the VMEM instr count).
// Edge metadata via wave-uniform scalar loads (readfirstlane'd bounds).
__global__ __launch_bounds__(256) void k_gather(const int* __restrict__ offs,
                                                const int2* __restrict__ csr2,
                                                const float* __restrict__ Ain,
                                                const float* __restrict__ g1,
                                                const float* __restrict__ g2,
                                                const float* __restrict__ murs,
                                                const float* __restrict__ t_in,
                                                float* __restrict__ h2,
                                                float* __restrict__ part2) {
    int bid = blockIdx.x;
    int xcd     = bid & 7;
    int seq     = bid >> 3;
    int pairIdx = seq >> 10;       // 0..2
    int nchunk  = seq & 1023;      // 0..1023
    int wv   = threadIdx.x >> 6;
    int lane = threadIdx.x & 63;
    int half = lane >> 5;
    int l5   = lane & 31;
    int n  = __builtin_amdgcn_readfirstlane(nchunk * 4 + wv);
    int bp = xcd + 8 * (2 * pairIdx + half);   // 0..47
    int b  = bp / Pc;
    int h0 = l5 * 2;

    const float* base = Ain + (size_t)bp * NHc + h0;
    int s0 = __builtin_amdgcn_readfirstlane(offs[n]);
    int s1 = __builtin_amdgcn_readfirstlane(offs[n + 1]);

    f32x2 a0 = {0.f, 0.f}, a1 = {0.f, 0.f}, a2 = {0.f, 0.f}, a3 = {0.f, 0.f};
    f32x2 a4 = {0.f, 0.f}, a5 = {0.f, 0.f}, a6 = {0.f, 0.f}, a7 = {0.f, 0.f};
    int idx = s0;
    for (; idx + 8 <= s1; idx += 8) {
        int2 e0 = csr2[idx],     e1 = csr2[idx + 1];
        int2 e2 = csr2[idx + 2], e3 = csr2[idx + 3];
        int2 e4 = csr2[idx + 4], e5 = csr2[idx + 5];
        int2 e6 = csr2[idx + 6], e7 = csr2[idx + 7];
        f32x2 v0 = *(const f32x2*)(base + e0.x);
        f32x2 v1 = *(const f32x2*)(base + e1.x);
        f32x2 v2 = *(const f32x2*)(base + e2.x);
        f32x2 v3 = *(const f32x2*)(base + e3.x);
        f32x2 v4 = *(const f32x2*)(base + e4.x);
        f32x2 v5 = *(const f32x2*)(base + e5.x);
        f32x2 v6 = *(const f32x2*)(base + e6.x);
        f32x2 v7 = *(const f32x2*)(base + e7.x);
        a0.x = fmaf(__int_as_float(e0.y), v0.x, a0.x); a0.y = fmaf(__int_as_float(e0.y), v0.y, a0.y);
        a1.x = fmaf(__int_as_float(e1.y), v1.x, a1.x); a1.y = fmaf(__int_as_float(e1.y), v1.y, a1.y);
        a2.x = fmaf(__int_as_float(e2.y), v2.x, a2.x); a2.y = fmaf(__int_as_float(e2.y), v2.y, a2.y);
        a3.x = fmaf(__int_as_float(e3.y), v3.x, a3.x); a3.y = fmaf(__int_as_float(e3.y), v3.y, a3.y);
        a4.x = fmaf(__int_as_float(e4.y), v4.x, a4.x); a4.y = fmaf(__int_as_float(e4.y), v4.y, a4.y);
        a5.x = fmaf(__int_as_float(e5.y), v5.x, a5.x); a5.y = fmaf(__int_as_float(e5.y), v5.y, a5.y);
        a6.x = fmaf(__int_as_float(e6.y), v6.x, a6.x); a6.y = fmaf(__int_as_float(e6.y), v6.y, a6.y);
        a7.x = fmaf(__int_as_float(e7.y), v7.x, a7.x); a7.y = fmaf(__int_as_float(e7.y), v7.y, a7.y);
    }
    for (; idx < s1; ++idx) {
        int2 e = csr2[idx];
        f32x2 v = *(const f32x2*)(base + e.x);
        a0.x = fmaf(__int_as_float(e.y), v.x, a0.x);
        a0.y = fmaf(__int_as_float(e.y), v.y, a0.y);
    }
    f32x2 acc = ((a0 + a1) + (a2 + a3)) + ((a4 + a5) + (a6 + a7));

    float mu = murs[bp * 2], rs = murs[bp * 2 + 1];
    f32x2 gg1 = *(const f32x2*)(g1 + n * Hc + h0);
    f32x2 gg2 = *(const f32x2*)(g2 + n * Hc + h0);
    f32x2 tt  = *(const f32x2*)(t_in + b * Hc + h0);
    float vx = rs * (acc.x - mu * gg1.x) + gg2.x + tt.x;
    float vy = rs * (acc.y - mu * gg1.y) + gg2.y + tt.y;
    f32x2 outv = {vx, vy};
    *(f32x2*)(h2 + (size_t)bp * NHc + n * Hc + h0) = outv;

    float s = vx + vy, ss = vx * vx + vy * vy;
    // butterfly within each 32-lane half (masks <= 16 stay in-half)
    #pragma unroll
    for (int m = 16; m; m >>= 1) { s += __shfl_xor(s, m); ss += __shfl_xor(ss, m); }
    if (l5 == 0) {
        part2[((size_t)bp * Nc + n) * 2]     = s;
        part2[((size_t)bp * Nc + n) * 2 + 1] = ss;
    }
}

// ---------------- apply LN2 + 1x1 conv over P (h2 may alias out!) ----------------
__global__ __launch_bounds__(256) void k_conv(const float* h2,
                                              const float* __restrict__ murs,
                                              const float* __restrict__ tnw, const float* __restrict__ tnb,
                                              const float* __restrict__ cw, const float* __restrict__ cb,
                                              float* out) {
    int tid = blockIdx.x * 256 + threadIdx.x;  // B * NHc/4 threads
    int b  = tid >> 16;           // / (NHc/4)
    int i4 = tid & 65535;
    size_t e0 = (size_t)i4 * 4;
    float4 w4 = *(const float4*)(tnw + e0);
    float4 b4 = *(const float4*)(tnb + e0);
    float v[Pc][4];
    #pragma unroll
    for (int p = 0; p < Pc; ++p) {
        int bp = b * Pc + p;
        float mu = murs[bp * 2], rs = murs[bp * 2 + 1];
        float4 h = *(const float4*)(h2 + (size_t)bp * NHc + e0);
        v[p][0] = (h.x - mu) * rs * w4.x + b4.x;
        v[p][1] = (h.y - mu) * rs * w4.y + b4.y;
        v[p][2] = (h.z - mu) * rs * w4.z + b4.z;
        v[p][3] = (h.w - mu) * rs * w4.w + b4.w;
    }
    #pragma unroll
    for (int q = 0; q < Pc; ++q) {
        float cbq = cb[q];
        float o0 = cbq, o1 = cbq, o2 = cbq, o3 = cbq;
        #pragma unroll
        for (int p = 0; p < Pc; ++p) {
            float wqp = cw[q * Pc + p];
            o0 = fmaf(v[p][0], wqp, o0);
            o1 = fmaf(v[p][1], wqp, o1);
            o2 = fmaf(v[p][2], wqp, o2);
            o3 = fmaf(v[p][3], wqp, o3);
        }
        float4 o = {o0, o1, o2, o3};
        *(float4*)(out + (size_t)(b * Pc + q) * NHc + e0) = o;
    }
}

extern "C" void kernel_launch(void* const* d_in, const int* in_sizes, int n_in,
                              void* d_out, int out_size, void* d_ws, size_t ws_size,
                              hipStream_t stream) {
    (void)in_sizes; (void)n_in; (void)out_size; (void)ws_size;
    const float* x     = (const float*)d_in[0];
    const int*   ei    = (const int*)  d_in[1];
    const float* timev = (const float*)d_in[2];
    const float* cond  = (const float*)d_in[3];
    const float* tp_w1 = (const float*)d_in[4];
    const float* tp_b1 = (const float*)d_in[5];
    const float* tp_w2 = (const float*)d_in[6];
    const float* tp_b2 = (const float*)d_in[7];
    const float* cp_w1 = (const float*)d_in[8];
    const float* cp_b1 = (const float*)d_in[9];
    const float* cp_w2 = (const float*)d_in[10];
    const float* cp_b2 = (const float*)d_in[11];
    const float* gn_w  = (const float*)d_in[12];
    const float* gn_b  = (const float*)d_in[13];
    const float* tn_w  = (const float*)d_in[14];
    const float* tn_b  = (const float*)d_in[15];
    const float* cw    = (const float*)d_in[16];
    const float* cb    = (const float*)d_in[17];
    float* out = (float*)d_out;

    char* w = (char*)d_ws;
    size_t off = 0;
    auto alloc = [&](size_t bytes) {
        void* p = w + off;
        off = (off + bytes + 255) & ~(size_t)255;
        return p;
    };
    float* bufA    = (float*)alloc((size_t)ROWS * Hc * sizeof(float)); // A = h1*gnw
    float* part1   = (float*)alloc((size_t)BPc * 64 * 2 * 4);
    float* part2   = (float*)alloc((size_t)BPc * Nc * 2 * 4);
    float* murs1   = (float*)alloc(96 * 4);
    float* murs2   = (float*)alloc(96 * 4);
    float* t_ws    = (float*)alloc(256 * 4);
    float* dis     = (float*)alloc(Nc * 4);
    int2*  csr2    = (int2*)alloc((size_t)Ec * 8);
    float* g1      = (float*)alloc((size_t)NHc * 4);
    float* g2      = (float*)alloc((size_t)NHc * 4);
    int*   deg     = (int*)alloc(Nc * 4);
    int*   offs    = (int*)alloc((Nc + 1) * 4);
    int*   cursor  = (int*)alloc(Nc * 4);
    float* h2 = out;  // gather output lives in d_out; k_conv is alias-safe

    hipMemsetAsync(deg, 0, Nc * sizeof(int), stream);
    k_tproj<<<1, 256, 0, stream>>>(timev, tp_w1, tp_b1, tp_w2, tp_b2, t_ws);
    k_deg<<<Ec / 256, 256, 0, stream>>>(ei + Ec, deg);
    k_scan<<<1, 1024, 0, stream>>>(deg, offs, cursor, dis);
    k_fill<<<Ec / 256, 256, 0, stream>>>(ei, cursor, dis, csr2);
    k_gw<<<Nc, 128, 0, stream>>>(offs, csr2, gn_w, gn_b, g1, g2);
    k_mlp<<<ROWS / 256, 256, 0, stream>>>(cond, x, cp_w1, cp_b1, cp_w2, cp_b2, gn_w, bufA, part1);
    k_finalize<<<BPc, 256, 0, stream>>>(part1, 64, murs1);
    k_gather<<<8 * 3 * 1024, 256, 0, stream>>>(offs, csr2, bufA, g1, g2,
                                               murs1, t_ws, h2, part2);
    k_finalize<<<BPc, 256, 0, stream>>>(part2, Nc, murs2);
    k_conv<<<(Bc * NHc / 4) / 256, 256, 0, stream>>>(h2, murs2, tn_w, tn_b, cw, cb, out);
}

// Round 6
// 130.635 us; speedup vs baseline: 3.8214x; 1.2453x over previous
//
#include <hip/hip_runtime.h>
#include <hip/hip_bf16.h>

#define Bc   4
#define Pc   12
#define Nc   4096
#define Hc   64
#define TDc  128
#define Ec   65536
#define BPc  48
#define Gg   6            // bp-slices per XCD group (bp = g + 8*j, j<6)
#define NHc  (Nc*Hc)      // 262144
#define ROWS (BPc*Nc)     // 196608
#define EPSc 1e-5f

typedef float    f32x4 __attribute__((ext_vector_type(4)));
typedef float    f32x2 __attribute__((ext_vector_type(2)));
typedef short    s16x4 __attribute__((ext_vector_type(4)));
typedef _Float16 f16x4 __attribute__((ext_vector_type(4)));
typedef _Float16 f16x8 __attribute__((ext_vector_type(8)));

__device__ inline short f2bf(float f) {
    union { float f; unsigned u; } v; v.f = f;
    unsigned r = v.u + 0x7FFFu + ((v.u >> 16) & 1u);
    return (short)(r >> 16);
}
__device__ inline s16x4 f2bf4(f32x4 v) {
    s16x4 o;
    o.x = f2bf(v.x); o.y = f2bf(v.y); o.z = f2bf(v.z); o.w = f2bf(v.w);
    return o;
}

// ---------------- time projection: t[b,h] = MLP(time[b,:]) ----------------
__global__ void k_tproj(const float* __restrict__ timev,
                        const float* __restrict__ w1, const float* __restrict__ b1,
                        const float* __restrict__ w2, const float* __restrict__ b2,
                        float* __restrict__ t_out) {
    __shared__ float s_time[Bc * TDc];
    __shared__ float s_hid[Bc * Hc];
    int t = threadIdx.x;
    for (int i = t; i < Bc * TDc; i += 256) s_time[i] = timev[i];
    __syncthreads();
    int b = t >> 6, j = t & 63;
    float acc = b1[j];
    for (int k = 0; k < TDc; ++k) acc = fmaf(s_time[b * TDc + k], w1[j * TDc + k], acc);
    s_hid[b * Hc + j] = fmaxf(acc, 0.f);
    __syncthreads();
    float acc2 = b2[j];
    for (int k = 0; k < Hc; ++k) acc2 = fmaf(s_hid[b * Hc + k], w2[j * Hc + k], acc2);
    t_out[b * Hc + j] = acc2;
}

// ---------------- degree count ----------------
__global__ void k_deg(const int* __restrict__ col, int* __restrict__ deg) {
    int e = blockIdx.x * 256 + threadIdx.x;
    atomicAdd(&deg[col[e]], 1);
}

// ---------------- exclusive scan over 4096 degrees + dis = deg^-1/2 ----------------
__global__ __launch_bounds__(1024) void k_scan(const int* __restrict__ deg,
                                               int* __restrict__ offs,
                                               int* __restrict__ cursor,
                                               float* __restrict__ dis) {
    __shared__ int part[1024];
    int t = threadIdx.x;
    int d0 = deg[t * 4], d1 = deg[t * 4 + 1], d2 = deg[t * 4 + 2], d3 = deg[t * 4 + 3];
    part[t] = d0 + d1 + d2 + d3;
    __syncthreads();
    for (int off = 1; off < 1024; off <<= 1) {
        int v = (t >= off) ? part[t - off] : 0;
        __syncthreads();
        part[t] += v;
        __syncthreads();
    }
    int base = (t ? part[t - 1] : 0);
    offs[t * 4]     = base;
    offs[t * 4 + 1] = base + d0;
    offs[t * 4 + 2] = base + d0 + d1;
    offs[t * 4 + 3] = base + d0 + d1 + d2;
    if (t == 1023) offs[4096] = part[1023];
    cursor[t * 4]     = base;
    cursor[t * 4 + 1] = base + d0;
    cursor[t * 4 + 2] = base + d0 + d1;
    cursor[t * 4 + 3] = base + d0 + d1 + d2;
    dis[t * 4]     = d0 > 0 ? rsqrtf((float)d0) : 0.f;
    dis[t * 4 + 1] = d1 > 0 ? rsqrtf((float)d1) : 0.f;
    dis[t * 4 + 2] = d2 > 0 ? rsqrtf((float)d2) : 0.f;
    dis[t * 4 + 3] = d3 > 0 ? rsqrtf((float)d3) : 0.f;
}

// ---------------- CSR fill: csr2 = {src, bits(w)} ----------------
__global__ void k_fill(const int* __restrict__ ei, int* __restrict__ cursor,
                       const float* __restrict__ dis,
                       int2* __restrict__ csr2) {
    int e = blockIdx.x * 256 + threadIdx.x;
    int r = ei[e], c = ei[Ec + e];
    int pos = atomicAdd(&cursor[c], 1);
    int2 v;
    v.x = r;
    v.y = __float_as_int(dis[r] * dis[c]);
    csr2[pos] = v;
}

// ---------------- g1 = gather(gnw), g2 = gather(gnb) ----------------
__global__ __launch_bounds__(128) void k_gw(const int* __restrict__ offs,
                                            const int2* __restrict__ csr2,
                                            const float* __restrict__ gnw,
                                            const float* __restrict__ gnb,
                                            float* __restrict__ g1, float* __restrict__ g2) {
    int n = blockIdx.x;
    int wave = threadIdx.x >> 6, lane = threadIdx.x & 63;
    const float* src = wave ? gnb : gnw;
    float* dst = wave ? g2 : g1;
    int s0 = __builtin_amdgcn_readfirstlane(offs[n]);
    int s1 = __builtin_amdgcn_readfirstlane(offs[n + 1]);
    float a0 = 0.f, a1 = 0.f, a2 = 0.f, a3 = 0.f;
    int i = s0;
    for (; i + 4 <= s1; i += 4) {
        int2 e0 = csr2[i], e1 = csr2[i + 1], e2 = csr2[i + 2], e3 = csr2[i + 3];
        a0 = fmaf(__int_as_float(e0.y), src[e0.x * Hc + lane], a0);
        a1 = fmaf(__int_as_float(e1.y), src[e1.x * Hc + lane], a1);
        a2 = fmaf(__int_as_float(e2.y), src[e2.x * Hc + lane], a2);
        a3 = fmaf(__int_as_float(e3.y), src[e3.x * Hc + lane], a3);
    }
    for (; i < s1; ++i) {
        int2 e = csr2[i];
        a0 = fmaf(__int_as_float(e.y), src[e.x * Hc + lane], a0);
    }
    dst[n * Hc + lane] = (a0 + a1) + (a2 + a3);
}

// ---------------- MFMA cond-MLP -> Af[g][n][j][h] fp16 (group-transposed); LN1 stats ----
// Layer-1 D-fragment == layer-2 B-fragment per lane (no LDS for the MLP itself).
// Per-wave LDS tile transposes fragments to node-major fp16 rows for coalesced stores.
__global__ __launch_bounds__(256) void k_mlp(const float* __restrict__ cond,
                                             const float* __restrict__ x,
                                             const float* __restrict__ w1, const float* __restrict__ b1,
                                             const float* __restrict__ w2, const float* __restrict__ b2,
                                             const float* __restrict__ gnw,
                                             _Float16* __restrict__ Af, float* __restrict__ part1) {
    __shared__ __align__(16) _Float16 s_h[4][16][72];
    int lane = threadIdx.x & 63;
    int wv   = threadIdx.x >> 6;
    int r = lane & 15, g = lane >> 4;
    int bp = blockIdx.x >> 4;
    int g4 = bp & 7, j6 = bp >> 3;            // bp = g4 + 8*j6
    int nbase = (blockIdx.x & 15) * 256;

    s16x4 a1[4][4], a2[4][4];
    f32x4 b1q[4], b2q[4];
    #pragma unroll
    for (int t = 0; t < 4; ++t) {
        #pragma unroll
        for (int kk = 0; kk < 4; ++kk) {
            a1[t][kk] = f2bf4(*(const f32x4*)(w1 + (16 * t + r) * Hc + kk * 16 + 4 * g));
            a2[t][kk] = f2bf4(*(const f32x4*)(w2 + (16 * t + r) * Hc + kk * 16 + 4 * g));
        }
        b1q[t] = *(const f32x4*)(b1 + 16 * t + 4 * g);
        b2q[t] = *(const f32x4*)(b2 + 16 * t + 4 * g);
    }

    float s = 0.f, ss = 0.f;
    int blockRow = blockIdx.x * 256;
    int nl = lane >> 3, hq = (lane & 7) * 8;
    #pragma unroll
    for (int c = 0; c < 4; ++c) {
        int row = blockRow + wv * 64 + c * 16 + r;
        int n   = row & (Nc - 1);
        // layer 1
        s16x4 bc[4];
        #pragma unroll
        for (int kk = 0; kk < 4; ++kk)
            bc[kk] = f2bf4(*(const f32x4*)(cond + (size_t)row * Hc + kk * 16 + 4 * g));
        s16x4 hB[4];
        #pragma unroll
        for (int t = 0; t < 4; ++t) {
            f32x4 acc = {0.f, 0.f, 0.f, 0.f};
            #pragma unroll
            for (int kk = 0; kk < 4; ++kk)
                acc = __builtin_amdgcn_mfma_f32_16x16x16bf16_1k(a1[t][kk], bc[kk], acc, 0, 0, 0);
            acc += b1q[t];
            f32x4 h;
            h.x = fmaxf(acc.x, 0.f); h.y = fmaxf(acc.y, 0.f);
            h.z = fmaxf(acc.z, 0.f); h.w = fmaxf(acc.w, 0.f);
            hB[t] = f2bf4(h);
        }
        // layer 2 + residual + gnw scale -> fp16 into per-wave LDS tile
        #pragma unroll
        for (int t = 0; t < 4; ++t) {
            f32x4 acc = {0.f, 0.f, 0.f, 0.f};
            #pragma unroll
            for (int kk = 0; kk < 4; ++kk)
                acc = __builtin_amdgcn_mfma_f32_16x16x16bf16_1k(a2[t][kk], hB[kk], acc, 0, 0, 0);
            f32x4 x4 = *(const f32x4*)(x + (size_t)row * Hc + 16 * t + 4 * g);
            f32x4 o = acc + b2q[t] + x4;
            s  += o.x + o.y + o.z + o.w;
            ss += o.x * o.x + o.y * o.y + o.z * o.z + o.w * o.w;
            f32x4 gw4 = *(const f32x4*)(gnw + n * Hc + 16 * t + 4 * g);
            f32x4 av = o * gw4;
            *(f16x4*)&s_h[wv][r][16 * t + 4 * g] = __builtin_convertvector(av, f16x4);
        }
        __syncthreads();
        // transpose read-back: 8 lanes per node row, 16 B each -> coalesced f16 stores
        #pragma unroll
        for (int p = 0; p < 2; ++p) {
            f16x8 v = *(const f16x8*)&s_h[wv][p * 8 + nl][hq];
            int nn = nbase + wv * 64 + c * 16 + p * 8 + nl;
            *(f16x8*)(Af + (((size_t)g4 * Nc + nn) * Gg + j6) * Hc + hq) = v;
        }
        __syncthreads();
    }
    for (int off = 32; off; off >>= 1) { s += __shfl_down(s, off); ss += __shfl_down(ss, off); }
    if (lane == 0) {
        int idx = (blockIdx.x & 15) * 4 + wv;  // 0..63
        part1[(bp * 64 + idx) * 2]     = s;
        part1[(bp * 64 + idx) * 2 + 1] = ss;
    }
}

// ---------------- finalize LN stats: mu, rsqrt(var+eps) per bp ----------------
__global__ __launch_bounds__(256) void k_finalize(const float* __restrict__ part, int cnt,
                                                  float* __restrict__ murs) {
    int bp = blockIdx.x;
    float s = 0.f, ss = 0.f;
    for (int i = threadIdx.x; i < cnt; i += 256) {
        s  += part[(bp * cnt + i) * 2];
        ss += part[(bp * cnt + i) * 2 + 1];
    }
    __shared__ float ls[4], lss[4];
    for (int off = 32; off; off >>= 1) { s += __shfl_down(s, off); ss += __shfl_down(ss, off); }
    int w = threadIdx.x >> 6, l = threadIdx.x & 63;
    if (l == 0) { ls[w] = s; lss[w] = ss; }
    __syncthreads();
    if (threadIdx.x == 0) {
        s  = ls[0] + ls[1] + ls[2] + ls[3];
        ss = lss[0] + lss[1] + lss[2] + lss[3];
        float mu = s / (float)NHc;
        float var = ss / (float)NHc - mu * mu;
        murs[bp * 2]     = mu;
        murs[bp * 2 + 1] = rsqrtf(var + EPSc);
    }
}

// ---------------- LGConv gather: 1 n x 6 bp per wave, fp16 dwordx4 lanes ----------------
// Af[g][n][j][h]: one XCD group's slice = 4096*384*2B = 3 MB -> fits 4 MB L2 (bid&7 pin).
// Per edge: ONE global_load_dwordx4 serves 6 bp slices (48 lanes x 16 B = 768 B row).
// Edge metadata via wave-uniform scalar loads (readfirstlane'd bounds).
__global__ __launch_bounds__(256) void k_gather(const int* __restrict__ offs,
                                                const int2* __restrict__ csr2,
                                                const _Float16* __restrict__ Af,
                                                const float* __restrict__ g1,
                                                const float* __restrict__ g2,
                                                const float* __restrict__ murs,
                                                const float* __restrict__ t_in,
                                                float* __restrict__ h2,
                                                float* __restrict__ part2) {
    int bid = blockIdx.x;
    int g   = bid & 7;
    int seq = bid >> 3;            // 0..1023
    int wv = threadIdx.x >> 6, lane = threadIdx.x & 63;
    int n  = __builtin_amdgcn_readfirstlane(seq * 4 + wv);
    int jj = lane >> 3;            // 0..7 (6,7 idle)
    int jc = jj < Gg ? jj : 0;
    int h0 = (lane & 7) * 8;
    const _Float16* base = Af + (size_t)g * (Nc * Gg * Hc) + jc * Hc + h0;
    int s0 = __builtin_amdgcn_readfirstlane(offs[n]);
    int s1 = __builtin_amdgcn_readfirstlane(offs[n + 1]);

    float acc[8];
    #pragma unroll
    for (int i = 0; i < 8; ++i) acc[i] = 0.f;

    int idx = s0;
    for (; idx + 4 <= s1; idx += 4) {
        int2 e0 = csr2[idx],     e1 = csr2[idx + 1];
        int2 e2 = csr2[idx + 2], e3 = csr2[idx + 3];
        f16x8 v0 = *(const f16x8*)(base + (size_t)e0.x * (Gg * Hc));
        f16x8 v1 = *(const f16x8*)(base + (size_t)e1.x * (Gg * Hc));
        f16x8 v2 = *(const f16x8*)(base + (size_t)e2.x * (Gg * Hc));
        f16x8 v3 = *(const f16x8*)(base + (size_t)e3.x * (Gg * Hc));
        float w0 = __int_as_float(e0.y), w1 = __int_as_float(e1.y);
        float w2 = __int_as_float(e2.y), w3 = __int_as_float(e3.y);
        #pragma unroll
        for (int i = 0; i < 8; ++i) {
            acc[i] = fmaf(w0, (float)v0[i], acc[i]);
            acc[i] = fmaf(w1, (float)v1[i], acc[i]);
            acc[i] = fmaf(w2, (float)v2[i], acc[i]);
            acc[i] = fmaf(w3, (float)v3[i], acc[i]);
        }
    }
    for (; idx < s1; ++idx) {
        int2 e = csr2[idx];
        f16x8 v = *(const f16x8*)(base + (size_t)e.x * (Gg * Hc));
        float w = __int_as_float(e.y);
        #pragma unroll
        for (int i = 0; i < 8; ++i) acc[i] = fmaf(w, (float)v[i], acc[i]);
    }

    int bp = g + 8 * jc;
    int b  = bp / Pc;
    float mu = murs[bp * 2], rs = murs[bp * 2 + 1];
    f32x4 g1a = *(const f32x4*)(g1 + n * Hc + h0);
    f32x4 g1b = *(const f32x4*)(g1 + n * Hc + h0 + 4);
    f32x4 g2a = *(const f32x4*)(g2 + n * Hc + h0);
    f32x4 g2b = *(const f32x4*)(g2 + n * Hc + h0 + 4);
    f32x4 tta = *(const f32x4*)(t_in + b * Hc + h0);
    f32x4 ttb = *(const f32x4*)(t_in + b * Hc + h0 + 4);
    f32x4 va, vb;
    va.x = rs * (acc[0] - mu * g1a.x) + g2a.x + tta.x;
    va.y = rs * (acc[1] - mu * g1a.y) + g2a.y + tta.y;
    va.z = rs * (acc[2] - mu * g1a.z) + g2a.z + tta.z;
    va.w = rs * (acc[3] - mu * g1a.w) + g2a.w + tta.w;
    vb.x = rs * (acc[4] - mu * g1b.x) + g2b.x + ttb.x;
    vb.y = rs * (acc[5] - mu * g1b.y) + g2b.y + ttb.y;
    vb.z = rs * (acc[6] - mu * g1b.z) + g2b.z + ttb.z;
    vb.w = rs * (acc[7] - mu * g1b.w) + g2b.w + ttb.w;

    float s  = (va.x + va.y) + (va.z + va.w) + (vb.x + vb.y) + (vb.z + vb.w);
    float ss = va.x * va.x + va.y * va.y + va.z * va.z + va.w * va.w
             + vb.x * vb.x + vb.y * vb.y + vb.z * vb.z + vb.w * vb.w;
    #pragma unroll
    for (int m = 4; m; m >>= 1) { s += __shfl_xor(s, m); ss += __shfl_xor(ss, m); }

    if (jj < Gg) {
        float* op = h2 + (size_t)bp * NHc + n * Hc + h0;
        *(f32x4*)op       = va;
        *(f32x4*)(op + 4) = vb;
        if ((lane & 7) == 0) {
            part2[((size_t)bp * Nc + n) * 2]     = s;
            part2[((size_t)bp * Nc + n) * 2 + 1] = ss;
        }
    }
}

// ---------------- apply LN2 + 1x1 conv over P (h2 may alias out!) ----------------
__global__ __launch_bounds__(256) void k_conv(const float* h2,
                                              const float* __restrict__ murs,
                                              const float* __restrict__ tnw, const float* __restrict__ tnb,
                                              const float* __restrict__ cw, const float* __restrict__ cb,
                                              float* out) {
    int tid = blockIdx.x * 256 + threadIdx.x;  // B * NHc/4 threads
    int b  = tid >> 16;           // / (NHc/4)
    int i4 = tid & 65535;
    size_t e0 = (size_t)i4 * 4;
    float4 w4 = *(const float4*)(tnw + e0);
    float4 b4 = *(const float4*)(tnb + e0);
    float v[Pc][4];
    #pragma unroll
    for (int p = 0; p < Pc; ++p) {
        int bp = b * Pc + p;
        float mu = murs[bp * 2], rs = murs[bp * 2 + 1];
        float4 h = *(const float4*)(h2 + (size_t)bp * NHc + e0);
        v[p][0] = (h.x - mu) * rs * w4.x + b4.x;
        v[p][1] = (h.y - mu) * rs * w4.y + b4.y;
        v[p][2] = (h.z - mu) * rs * w4.z + b4.z;
        v[p][3] = (h.w - mu) * rs * w4.w + b4.w;
    }
    #pragma unroll
    for (int q = 0; q < Pc; ++q) {
        float cbq = cb[q];
        float o0 = cbq, o1 = cbq, o2 = cbq, o3 = cbq;
        #pragma unroll
        for (int p = 0; p < Pc; ++p) {
            float wqp = cw[q * Pc + p];
            o0 = fmaf(v[p][0], wqp, o0);
            o1 = fmaf(v[p][1], wqp, o1);
            o2 = fmaf(v[p][2], wqp, o2);
            o3 = fmaf(v[p][3], wqp, o3);
        }
        float4 o = {o0, o1, o2, o3};
        *(float4*)(out + (size_t)(b * Pc + q) * NHc + e0) = o;
    }
}

extern "C" void kernel_launch(void* const* d_in, const int* in_sizes, int n_in,
                              void* d_out, int out_size, void* d_ws, size_t ws_size,
                              hipStream_t stream) {
    (void)in_sizes; (void)n_in; (void)out_size; (void)ws_size;
    const float* x     = (const float*)d_in[0];
    const int*   ei    = (const int*)  d_in[1];
    const float* timev = (const float*)d_in[2];
    const float* cond  = (const float*)d_in[3];
    const float* tp_w1 = (const float*)d_in[4];
    const float* tp_b1 = (const float*)d_in[5];
    const float* tp_w2 = (const float*)d_in[6];
    const float* tp_b2 = (const float*)d_in[7];
    const float* cp_w1 = (const float*)d_in[8];
    const float* cp_b1 = (const float*)d_in[9];
    const float* cp_w2 = (const float*)d_in[10];
    const float* cp_b2 = (const float*)d_in[11];
    const float* gn_w  = (const float*)d_in[12];
    const float* gn_b  = (const float*)d_in[13];
    const float* tn_w  = (const float*)d_in[14];
    const float* tn_b  = (const float*)d_in[15];
    const float* cw    = (const float*)d_in[16];
    const float* cb    = (const float*)d_in[17];
    float* out = (float*)d_out;

    char* w = (char*)d_ws;
    size_t off = 0;
    auto alloc = [&](size_t bytes) {
        void* p = w + off;
        off = (off + bytes + 255) & ~(size_t)255;
        return p;
    };
    _Float16* Af   = (_Float16*)alloc((size_t)ROWS * Hc * sizeof(_Float16)); // 25 MB
    float* part1   = (float*)alloc((size_t)BPc * 64 * 2 * 4);
    float* part2   = (float*)alloc((size_t)BPc * Nc * 2 * 4);
    float* murs1   = (float*)alloc(96 * 4);
    float* murs2   = (float*)alloc(96 * 4);
    float* t_ws    = (float*)alloc(256 * 4);
    float* dis     = (float*)alloc(Nc * 4);
    int2*  csr2    = (int2*)alloc((size_t)Ec * 8);
    float* g1      = (float*)alloc((size_t)NHc * 4);
    float* g2      = (float*)alloc((size_t)NHc * 4);
    int*   deg     = (int*)alloc(Nc * 4);
    int*   offs    = (int*)alloc((Nc + 1) * 4);
    int*   cursor  = (int*)alloc(Nc * 4);
    float* h2 = out;  // gather output lives in d_out; k_conv is alias-safe

    hipMemsetAsync(deg, 0, Nc * sizeof(int), stream);
    k_tproj<<<1, 256, 0, stream>>>(timev, tp_w1, tp_b1, tp_w2, tp_b2, t_ws);
    k_deg<<<Ec / 256, 256, 0, stream>>>(ei + Ec, deg);
    k_scan<<<1, 1024, 0, stream>>>(deg, offs, cursor, dis);
    k_fill<<<Ec / 256, 256, 0, stream>>>(ei, cursor, dis, csr2);
    k_gw<<<Nc, 128, 0, stream>>>(offs, csr2, gn_w, gn_b, g1, g2);
    k_mlp<<<ROWS / 256, 256, 0, stream>>>(cond, x, cp_w1, cp_b1, cp_w2, cp_b2, gn_w, Af, part1);
    k_finalize<<<BPc, 256, 0, stream>>>(part1, 64, murs1);
    k_gather<<<8 * 1024, 256, 0, stream>>>(offs, csr2, Af, g1, g2,
                                           murs1, t_ws, h2, part2);
    k_finalize<<<BPc, 256, 0, stream>>>(part2, Nc, murs2);
    k_conv<<<(Bc * NHc / 4) / 256, 256, 0, stream>>>(h2, murs2, tn_w, tn_b, cw, cb, out);
}